// Round 8
// baseline (250.713 us; speedup 1.0000x reference)
//
#include <hip/hip_runtime.h>
#include <stdint.h>
#include <stddef.h>

// ============================================================================
// HTensorSquare: out[b] = sum_paths alpha * einsum(uvw,ijk,bui,bvj->bwk)
// Irreps in/out: 64x0e + 32x1o + 16x2e  (DIM 240), B = 20000.
// Fused into 3 GEMMs, A-operand generated in registers, B = preprocessed bf16
// weights in MFMA-fragment tile order.  K folded by x@x symmetry (round 7).
// Round-8: bf16 x-tile in LDS (31.7 KB, was 62.5 KB f32) -> 3-4 blocks/CU
// (was 2).  All bf16 conversions RNE via v_cvt_pk_bf16_f32 (replaces the
// truncating v_perm pack -- error budget unchanged or better).  Reduction
// scratch reuses the x-tile LDS (x dead by then); GEMM0 reduces in 3 passes.
// ============================================================================

// ---------------------------------------------------------------------------
// Compile-time Clebsch-Gordan machinery (exact port of the reference numpy).
// ---------------------------------------------------------------------------
namespace cg {

struct Cx { double re, im; };
constexpr Cx cmul(Cx a, Cx b){ return { a.re*b.re - a.im*b.im, a.re*b.im + a.im*b.re }; }

constexpr double fact(int n){ double r = 1.0; for (int i = 2; i <= n; ++i) r *= (double)i; return r; }

constexpr double csqrt(double x){
  if (x <= 0.0) return 0.0;
  double r = x > 1.0 ? x : 1.0;
  for (int i = 0; i < 50; ++i) r = 0.5*(r + x/r);
  return r;
}

constexpr double neg1pow(int k){ return (k % 2 == 0) ? 1.0 : -1.0; }

constexpr double su2_cg(int j1,int m1,int j2,int m2,int j3,int m3){
  if (m3 != m1 + m2) return 0.0;
  int vmin = -j1 + j2 + m3;
  if (-j1 + m1 > vmin) vmin = -j1 + m1;
  if (0 > vmin) vmin = 0;
  int vmax = j2 + j3 + m1;
  if (j3 - j1 + j2 < vmax) vmax = j3 - j1 + j2;
  if (j3 + m3 < vmax) vmax = j3 + m3;
  if (vmax < vmin) return 0.0;
  double C = csqrt((2.0*j3 + 1.0)*fact(j3+j1-j2)*fact(j3-j1+j2)*fact(j1+j2-j3)
                   *fact(j3+m3)*fact(j3-m3)
                   /(fact(j1+j2+j3+1)*fact(j1-m1)*fact(j1+m1)*fact(j2-m2)*fact(j2+m2)));
  double S = 0.0;
  for (int v = vmin; v <= vmax; ++v)
    S += neg1pow(v + j2 + m2)*fact(j2+j3+m1-v)*fact(j1-m1+v)
       /(fact(v)*fact(j3-j1+j2-v)*fact(j3+m3-v)*fact(v+j1-j2-m3));
  return C*S;
}

struct QM { Cx v[5][5]; };
constexpr QM qmat(int l){
  QM q{};
  const double r2 = 0.70710678118654752440;
  for (int m = -l; m < 0; ++m){
    q.v[l+m][l-m] = Cx{ r2, 0.0 };       // q[l+m, l+|m|]
    q.v[l+m][l+m] = Cx{ 0.0, -r2 };      // q[l+m, l-|m|]
  }
  q.v[l][l] = Cx{ 1.0, 0.0 };
  for (int m = 1; m <= l; ++m){
    double s = neg1pow(m)*r2;
    q.v[l+m][l+m] = Cx{ s, 0.0 };
    q.v[l+m][l-m] = Cx{ 0.0, s };
  }
  Cx ph = (l % 4 == 0) ? Cx{1,0} : (l % 4 == 1) ? Cx{0,-1} : (l % 4 == 2) ? Cx{-1,0} : Cx{0,1};
  QM out{};
  for (int i = 0; i < 5; ++i) for (int j = 0; j < 5; ++j) out.v[i][j] = cmul(ph, q.v[i][j]);
  return out;
}

struct CGT { double v[5][5][5]; };
// Real-basis CG * sqrt(2*l3+1)   (matches reference CGS entries)
constexpr CGT cg_tab(int l1,int l2,int l3){
  double C[5][5][5] = {};
  for (int m1 = -l1; m1 <= l1; ++m1)
    for (int m2 = -l2; m2 <= l2; ++m2)
      for (int m3 = -l3; m3 <= l3; ++m3)
        C[l1+m1][l2+m2][l3+m3] = su2_cg(l1,m1,l2,m2,l3,m3);
  QM Q1 = qmat(l1), Q2 = qmat(l2), Q3 = qmat(l3);
  const int n1 = 2*l1+1, n2 = 2*l2+1, n3 = 2*l3+1;
  const double norm = csqrt(2.0*l3 + 1.0);
  CGT R{};
  for (int j = 0; j < n1; ++j)
    for (int l = 0; l < n2; ++l)
      for (int m = 0; m < n3; ++m){
        Cx s{0,0};
        for (int i = 0; i < n1; ++i)
          for (int k = 0; k < n2; ++k)
            for (int n = 0; n < n3; ++n){
              double c = C[i][k][n];
              if (c != 0.0){
                Cx q3c{ Q3.v[n][m].re, -Q3.v[n][m].im };   // conj(Q3.T)[m][n]
                Cx t = cmul(cmul(Q1.v[i][j], Q2.v[k][l]), q3c);
                s.re += t.re*c; s.im += t.im*c;
              }
            }
        R.v[j][l][m] = s.re * norm;
      }
  return R;
}

constexpr double tab_sumsq(const CGT& t, int n1, int n2, int n3){
  double s = 0;
  for (int i = 0; i < n1; ++i) for (int j = 0; j < n2; ++j) for (int k = 0; k < n3; ++k)
    s += t.v[i][j][k]*t.v[i][j][k];
  return s;
}

} // namespace cg

// Full tables for the 4 non-trivial paths
constexpr cg::CGT T121 = cg::cg_tab(1,2,1);
constexpr cg::CGT T211 = cg::cg_tab(2,1,1);
constexpr cg::CGT T112 = cg::cg_tab(1,1,2);
constexpr cg::CGT T222 = cg::cg_tab(2,2,2);
// Scalar constants for delta-structured paths
constexpr double C000 = cg::cg_tab(0,0,0).v[0][0][0];
constexpr double C011 = cg::cg_tab(0,1,1).v[0][0][0];
constexpr double C022 = cg::cg_tab(0,2,2).v[0][0][0];
constexpr double C101 = cg::cg_tab(1,0,1).v[0][0][0];
constexpr double C110 = cg::cg_tab(1,1,0).v[0][0][0];
constexpr double C220 = cg::cg_tab(2,2,0).v[0][0][0];
constexpr double C202 = cg::cg_tab(2,0,2).v[0][0][0];

// Sanity checks
static_assert(C000 > 0.99 && C000 < 1.01, "C000");
static_assert(C011 > 1.72 && C011 < 1.74, "C011");
static_assert(C101 > 1.72 && C101 < 1.74, "C101");
static_assert(C022 > 2.22 && C022 < 2.25, "C022");
static_assert(C202 > 2.22 && C202 < 2.25, "C202");
static_assert(C110*C110 > 0.332 && C110*C110 < 0.334, "C110");
static_assert(C220*C220 > 0.199 && C220*C220 < 0.201, "C220");
static_assert(cg::tab_sumsq(T121,3,5,3) > 8.9  && cg::tab_sumsq(T121,3,5,3) < 9.1,  "T121");
static_assert(cg::tab_sumsq(T211,5,3,3) > 8.9  && cg::tab_sumsq(T211,5,3,3) < 9.1,  "T211");
static_assert(cg::tab_sumsq(T112,3,3,5) > 24.9 && cg::tab_sumsq(T112,3,3,5) < 25.1, "T112");
static_assert(cg::tab_sumsq(T222,5,5,5) > 24.9 && cg::tab_sumsq(T222,5,5,5) < 25.1, "T222");

// The (2,1,1)->(1,2,1) fold requires C211[i][j][k] == C121[j][i][k].
constexpr double t121_t211_swapdiff(){
  double m = 0;
  for (int i = 0; i < 5; ++i)
    for (int j = 0; j < 3; ++j)
      for (int k = 0; k < 3; ++k){
        double d = T211.v[i][j][k] - T121.v[j][i][k];
        if (d < 0) d = -d;
        if (d > m) m = d;
      }
  return m;
}
static_assert(t121_t211_swapdiff() < 1e-9, "T211 != T121^T -- fold invalid");

// Normalization (fan-in per output irrep) folded into weights.
constexpr double A0 = 1.0/cg::csqrt(5376.0);
constexpr double A1 = 1.0/cg::csqrt(5120.0);
constexpr double A2 = 1.0/cg::csqrt(3328.0);

constexpr double S000 = A0*C000, S110 = A0*C110, S220 = A0*C220;
constexpr double S011 = A1*C011, S101 = A1*C101, S121 = A1, S211 = A1;
constexpr double S022 = A2*C022, S112 = A2,      S202 = A2*C202, S222 = A2;

// Folded K extents (bf16 elements), fragment-tiled layout:
// element (n = nt*16+col, k = s*32+kk) at base_g + (s*NT_g + nt)*512 + col*32 + kk.
constexpr int K0 = 4352, K1 = 2560, K2 = 2304;   // S0=136, S1=80, S2=72
constexpr int WT1_OFF = 64*K0;              // 278528
constexpr int WT2_OFF = WT1_OFF + 32*K1;    // 360448

// ---------------------------------------------------------------------------
// Device helpers
// ---------------------------------------------------------------------------
using short8  = __attribute__((ext_vector_type(8))) short;
using float4v = __attribute__((ext_vector_type(4))) float;

// RNE pack of two f32 -> packed 2x bf16 (one v_cvt_pk_bf16_f32).
__device__ __forceinline__ unsigned pkbf(float lo, float hi){
  unsigned r;
  asm("v_cvt_pk_bf16_f32 %0, %1, %2" : "=v"(r) : "v"(lo), "v"(hi));
  return r;
}

__device__ __forceinline__ short8 mkfrag(const float* s){
  union { short8 v; unsigned u[4]; } f;
  f.u[0] = pkbf(s[0], s[1]);
  f.u[1] = pkbf(s[2], s[3]);
  f.u[2] = pkbf(s[4], s[5]);
  f.u[3] = pkbf(s[6], s[7]);
  return f.v;
}

__device__ __forceinline__ short8 ldB(const unsigned short* p){
  return *reinterpret_cast<const short8*>(p);   // global_load_dwordx4
}

__device__ __forceinline__ float4v MFMA(short8 a, short8 b, float4v c){
  return __builtin_amdgcn_mfma_f32_16x16x32_bf16(a, b, c, 0, 0, 0);
}

__device__ __forceinline__ unsigned short f2bf_rne(float f){
  unsigned u = __builtin_bit_cast(unsigned, f);
  u += 0x7fffu + ((u >> 16) & 1u);
  return (unsigned short)(u >> 16);
}

// bf16 (LDS) -> f32: one shift.
__device__ __forceinline__ float bf2f(unsigned short h){
  return __builtin_bit_cast(float, (unsigned)h << 16);
}

// Load n consecutive bf16 from LDS (16B-aligned, n multiple of 8) -> f32 regs.
template<int N>
__device__ __forceinline__ void ldw(const unsigned short* p, float* dst){
  #pragma unroll
  for (int q = 0; q < N/8; ++q){
    union { short8 v; unsigned short u[8]; } t;
    t.v = *reinterpret_cast<const short8*>(p + q*8);
    #pragma unroll
    for (int i = 0; i < 8; ++i) dst[q*8 + i] = bf2f(t.u[i]);
  }
}

#define NZ(c) ((c) > 1e-12 || (c) < -1e-12)

constexpr int XSH = 248;  // x-tile LDS row stride (ushorts): 496B, 2-way banks

// ---------------------------------------------------------------------------
// Weight preprocessing v3: folded + fragment-tiled (identical to round 7).
// grid (136, 3), block 256.
// ---------------------------------------------------------------------------
__global__ __launch_bounds__(256)
void tsq_prep(const float* __restrict__ w0, const float* __restrict__ w1,
              const float* __restrict__ w2, const float* __restrict__ w3,
              const float* __restrict__ w4, const float* __restrict__ w5,
              const float* __restrict__ w6, const float* __restrict__ w7,
              const float* __restrict__ w8, const float* __restrict__ w9,
              const float* __restrict__ w10, unsigned short* __restrict__ wt){
  const int s   = blockIdx.x;
  const int g   = blockIdx.y;
  const int tid = threadIdx.x;

  const int lw  = 6 - g;                 // log2(Wn): 6,5,4
  const int Wn  = 1 << lw;               // 64,32,16
  const int NT  = Wn >> 4;               // 4,2,1
  int Smax;
  unsigned short* obase;
  if (g == 0){ Smax = 136; obase = wt; }
  else if (g == 1){ Smax = 80; obase = wt + WT1_OFF; }
  else { Smax = 72; obase = wt + WT2_OFF; }
  if (s >= Smax) return;

  __shared__ unsigned short tl[32*66];   // max 32 x (64+2)
  const int st = Wn + 2;

  // ---- phase 1: gather/scale/convert (with mirror folds), coalesced in n ----
  const int nel = 32 << lw;              // == NT*512
  for (int idx = tid; idx < nel; idx += 256){
    const int kk = idx >> lw, n = idx & (Wn - 1);
    float v;
    if (g == 0){
      if (s < 64){                                   // (0,0,0) u<32, all v
        const int u = s >> 1, vv = (s & 1)*32 + kk;
        v = w0[(u*64 + vv)*64 + n];
        if (s & 1) v += w0[(vv*64 + u)*64 + n];      // fold dropped (u>=32,v<32)
        v *= (float)S000;
      } else if (s < 96){                            // (0,0,0) u>=32, v>=32
        const int u = s - 32, vv = 32 + kk;
        v = w0[(u*64 + vv)*64 + n] * (float)S000;
      } else if (s < 128){                           // (1,1,0) K=u*32+v
        v = w4[((s-96)*32 + kk)*64 + n] * (float)S110;
      } else {                                       // (2,2,0) K=u*16+v
        v = w9[((s-128)*32 + kk)*64 + n] * (float)S220;
      }
    } else if (g == 1){
      const int k = s*32 + kk;
      if (s < 64){                                   // (0,1,1)+(1,0,1), K=A1*64+A0
        v = w1[((k&63)*32 + (k>>6))*32 + n] * (float)S011
          + w3[k*32 + n] * (float)S101;
      } else {                                       // (1,2,1)+(2,1,1), K=v2*32+u1
        const int kr = k - 2048;
        const int u1 = kr & 31, v2 = kr >> 5;
        v = w6[(u1*16 + v2)*32 + n] * (float)S121
          + w8[(v2*32 + u1)*32 + n] * (float)S211;
      }
    } else {
      const int k = s*32 + kk;
      if (s < 32){                                   // (0,2,2)+(2,0,2), K=v2*64+u0
        v = w2[((k&63)*16 + (k>>6))*16 + n] * (float)S022
          + w7[k*16 + n] * (float)S202;
      } else if (s < 64){                            // (1,1,2) K=u*32+v
        v = w5[(k-1024)*16 + n] * (float)S112;
      } else {                                       // (2,2,2) K=u*16+v
        v = w10[(k-2048)*16 + n] * (float)S222;
      }
    }
    tl[kk*st + n] = f2bf_rne(v);
  }
  __syncthreads();

  // ---- phase 2: contiguous fragment-order write ----
  unsigned short* o = obase + (size_t)s*NT*512;
  const int nout = NT*512;
  for (int idx = tid; idx < nout; idx += 256){
    const int nt  = idx >> 9;
    const int r   = idx & 511;
    const int col = r >> 5;
    const int kk  = r & 31;
    o[idx] = tl[kk*st + nt*16 + col];
  }
}

// ---------------------------------------------------------------------------
// Main kernel.  grid (3, 313), block 512 (8 waves).  blockIdx.x = GEMM id,
// blockIdx.y = batch tile of 64 rows.  x tile staged in LDS as bf16 (RNE):
// 64 x 248 ushorts = 31.7 KB -> 3-4 blocks/CU (was 2 at 62.5 KB f32).
// Reduction scratch reuses the x LDS as f32 (7936 floats); GEMM0 = 3 passes.
// ---------------------------------------------------------------------------
__global__ __launch_bounds__(512, 6)
void tsq_main(const float* __restrict__ x, const unsigned short* __restrict__ wt,
              float* __restrict__ out){
  __shared__ unsigned short lxh[64*XSH];
  const int g    = blockIdx.x;
  const int b0   = blockIdx.y * 64;
  const int tid  = threadIdx.x;
  const int wv   = tid >> 6;      // 0..7
  const int lane = tid & 63;
  const int col  = lane & 15;
  const int tg   = lane >> 4;
  const int fo   = col*32 + tg*8; // per-lane fragment offset within a 512-el tile

  // ---- stage x tile: f32 global -> RNE bf16 LDS (uint2 = 4 elems / store) ----
  for (int i = tid; i < 64*60; i += 512){
    const int r = i / 60, c = i - r*60;
    int gb = b0 + r; if (gb > 19999) gb = 19999;
    const float4 v = *(reinterpret_cast<const float4*>(x + (size_t)gb*240) + c);
    uint2 p; p.x = pkbf(v.x, v.y); p.y = pkbf(v.z, v.w);
    *reinterpret_cast<uint2*>(&lxh[r*XSH + c*4]) = p;
  }
  __syncthreads();

  const float4v z4 = {0.f, 0.f, 0.f, 0.f};

  if (g == 0){
    // ====== GEMM 0: out[:,0:64], K=4352, 2-way M (mh) x 4-way K (kh) ======
    const unsigned short* bpl = wt + fo;
    const int mh  = wv >> 2;
    const int kh  = wv & 3;
    const int par = kh & 1;       // s-parity for s<64 (constant per wave)

    float4v acc[2][4];
    #pragma unroll
    for (int mt = 0; mt < 2; ++mt)
      #pragma unroll
      for (int nt = 0; nt < 4; ++nt) acc[mt][nt] = z4;

    const unsigned short* rbase[2];
    #pragma unroll
    for (int mt = 0; mt < 2; ++mt) rbase[mt] = &lxh[(mh*32 + mt*16 + col)*XSH];

    // wA = x0 window for parity `par` (s<64); wB = x0 upper half (s>=64).
    float wA[2][8], wB[2][8];
    #pragma unroll
    for (int mt = 0; mt < 2; ++mt){
      ldw<8>(rbase[mt] + par*32 + tg*8, wA[mt]);
      ldw<8>(rbase[mt] + 32 + tg*8,     wB[mt]);
    }

    // --- (0,0,0) part A: s in [0,64), u = s>>1 (<32), window = wA ---
    for (int s = kh; s < 64; s += 4){
      short8 bf[4];
      #pragma unroll
      for (int nt = 0; nt < 4; ++nt) bf[nt] = ldB(bpl + (s*4 + nt)*512);
      const int u = s >> 1;
      #pragma unroll
      for (int mt = 0; mt < 2; ++mt){
        const float xu = bf2f(rbase[mt][u]);
        float sv[8];
        #pragma unroll
        for (int t = 0; t < 8; ++t) sv[t] = xu * wA[mt][t];
        const short8 af = mkfrag(sv);
        #pragma unroll
        for (int nt = 0; nt < 4; ++nt) acc[mt][nt] = MFMA(af, bf[nt], acc[mt][nt]);
      }
    }
    // --- (0,0,0) part B: s in [64,96), u = s-32 (>=32), window = wB ---
    for (int s = 64 + kh; s < 96; s += 4){
      short8 bf[4];
      #pragma unroll
      for (int nt = 0; nt < 4; ++nt) bf[nt] = ldB(bpl + (s*4 + nt)*512);
      const int u = s - 32;
      #pragma unroll
      for (int mt = 0; mt < 2; ++mt){
        const float xu = bf2f(rbase[mt][u]);
        float sv[8];
        #pragma unroll
        for (int t = 0; t < 8; ++t) sv[t] = xu * wB[mt][t];
        const short8 af = mkfrag(sv);
        #pragma unroll
        for (int nt = 0; nt < 4; ++nt) acc[mt][nt] = MFMA(af, bf[nt], acc[mt][nt]);
      }
    }
    // --- (1,1,0): s in [96,128), u = s-96, K=u*32+v ---
    float x1w[2][24];
    #pragma unroll
    for (int mt = 0; mt < 2; ++mt) ldw<24>(rbase[mt] + 64 + tg*24, x1w[mt]);
    for (int s = 96 + kh; s < 128; s += 4){
      short8 bf[4];
      #pragma unroll
      for (int nt = 0; nt < 4; ++nt) bf[nt] = ldB(bpl + (s*4 + nt)*512);
      const int u = s - 96;
      #pragma unroll
      for (int mt = 0; mt < 2; ++mt){
        const unsigned short* rb = rbase[mt];
        const float u0 = bf2f(rb[64+u*3]), u1 = bf2f(rb[64+u*3+1]), u2 = bf2f(rb[64+u*3+2]);
        float sv[8];
        #pragma unroll
        for (int t = 0; t < 8; ++t)
          sv[t] = fmaf(u0, x1w[mt][t*3], fmaf(u1, x1w[mt][t*3+1], u2*x1w[mt][t*3+2]));
        const short8 af = mkfrag(sv);
        #pragma unroll
        for (int nt = 0; nt < 4; ++nt) acc[mt][nt] = MFMA(af, bf[nt], acc[mt][nt]);
      }
    }
    // --- (2,2,0): s in [128,136), K=u*16+v ---
    {
      float xv[2][40];
      #pragma unroll
      for (int mt = 0; mt < 2; ++mt) ldw<40>(rbase[mt] + 160 + (tg&1)*40, xv[mt]);
      for (int s = 128 + kh; s < 136; s += 4){
        short8 bf[4];
        #pragma unroll
        for (int nt = 0; nt < 4; ++nt) bf[nt] = ldB(bpl + (s*4 + nt)*512);
        const int ub = (s - 128)*2 + (tg >> 1);
        #pragma unroll
        for (int mt = 0; mt < 2; ++mt){
          const unsigned short* rb = rbase[mt];
          float xu[5];
          #pragma unroll
          for (int i = 0; i < 5; ++i) xu[i] = bf2f(rb[160 + ub*5 + i]);
          float sv[8];
          #pragma unroll
          for (int t = 0; t < 8; ++t){
            float a = 0.f;
            #pragma unroll
            for (int i = 0; i < 5; ++i) a = fmaf(xu[i], xv[mt][t*5+i], a);
            sv[t] = a;
          }
          const short8 af = mkfrag(sv);
          #pragma unroll
          for (int nt = 0; nt < 4; ++nt) acc[mt][nt] = MFMA(af, bf[nt], acc[mt][nt]);
        }
      }
    }
    // --- 4-way K reduction, 3 passes of 16 KB (scratch = lxh as f32) ---
    __syncthreads();
    float* red = reinterpret_cast<float*>(lxh);
    #pragma unroll
    for (int p = 1; p <= 3; ++p){
      if (kh == p){
        #pragma unroll
        for (int mt = 0; mt < 2; ++mt)
          #pragma unroll
          for (int nt = 0; nt < 4; ++nt)
            #pragma unroll
            for (int r = 0; r < 4; ++r)
              red[mh*2048 + (mt*4 + nt)*256 + (tg*4 + r)*16 + col] = acc[mt][nt][r];
      }
      __syncthreads();
      if (kh == 0){
        #pragma unroll
        for (int mt = 0; mt < 2; ++mt)
          #pragma unroll
          for (int nt = 0; nt < 4; ++nt)
            #pragma unroll
            for (int r = 0; r < 4; ++r)
              acc[mt][nt][r] += red[mh*2048 + (mt*4 + nt)*256 + (tg*4 + r)*16 + col];
      }
      __syncthreads();
    }
    if (kh == 0){
      #pragma unroll
      for (int mt = 0; mt < 2; ++mt)
        #pragma unroll
        for (int r = 0; r < 4; ++r){
          const int b = b0 + mh*32 + mt*16 + tg*4 + r;
          if (b < 20000){
            #pragma unroll
            for (int nt = 0; nt < 4; ++nt)
              out[(size_t)b*240 + nt*16 + col] = acc[mt][nt][r];
          }
        }
    }

  } else if (g == 1){
    // ===== GEMM 1: out[:,64:160] (w*3+k), K=2560, 4-way M (mq) x 2-way K =====
    const unsigned short* bpl = wt + WT1_OFF + fo;
    const int mq = wv >> 1;
    const int kh = wv & 1;
    const unsigned short* rb = &lxh[(mq*16 + col)*XSH];

    float4v acc[3][2];
    #pragma unroll
    for (int k3 = 0; k3 < 3; ++k3)
      #pragma unroll
      for (int nt = 0; nt < 2; ++nt) acc[k3][nt] = z4;

    float w8[8];
    ldw<8>(rb + kh*32 + tg*8, w8);
    float x1w[24];
    ldw<24>(rb + 64 + tg*24, x1w);

    // --- (0,1,1)+(1,0,1) folded: s in [0,64), K=A1*64+A0 ---
    for (int s = kh; s < 64; s += 2){
      const short8 bf0 = ldB(bpl + (s*2    )*512);
      const short8 bf1 = ldB(bpl + (s*2 + 1)*512);
      const int m = s >> 1;
      const float c0 = bf2f(rb[64+m*3]), c1 = bf2f(rb[64+m*3+1]), c2 = bf2f(rb[64+m*3+2]);
      float sv0[8], sv1[8], sv2[8];
      #pragma unroll
      for (int t = 0; t < 8; ++t){
        const float xw = w8[t];
        sv0[t] = xw*c0; sv1[t] = xw*c1; sv2[t] = xw*c2;
      }
      const short8 a0 = mkfrag(sv0), a1 = mkfrag(sv1), a2 = mkfrag(sv2);
      acc[0][0] = MFMA(a0, bf0, acc[0][0]);
      acc[0][1] = MFMA(a0, bf1, acc[0][1]);
      acc[1][0] = MFMA(a1, bf0, acc[1][0]);
      acc[1][1] = MFMA(a1, bf1, acc[1][1]);
      acc[2][0] = MFMA(a2, bf0, acc[2][0]);
      acc[2][1] = MFMA(a2, bf1, acc[2][1]);
    }
    // --- (1,2,1)+(2,1,1) folded: s in [64,80), K=v2*32+u1, precontracted ---
    for (int s = 64 + kh; s < 80; s += 2){
      const short8 bf0 = ldB(bpl + (s*2    )*512);
      const short8 bf1 = ldB(bpl + (s*2 + 1)*512);
      const int v2 = s - 64;
      float xq[5];
      #pragma unroll
      for (int j = 0; j < 5; ++j) xq[j] = bf2f(rb[160 + v2*5 + j]);
      // t3[kk][i] = sum_j C121[i][j][kk] * xq[j]
      float t3[3][3];
      #pragma unroll
      for (int kk = 0; kk < 3; ++kk)
        #pragma unroll
        for (int i = 0; i < 3; ++i){
          float a = 0.f;
          #pragma unroll
          for (int j = 0; j < 5; ++j){
            const double cd = T121.v[i][j][kk];
            if (NZ(cd)) a = fmaf((float)cd, xq[j], a);
          }
          t3[kk][i] = a;
        }
      float sv0[8], sv1[8], sv2[8];
      #pragma unroll
      for (int t = 0; t < 8; ++t){
        const float a0_ = x1w[t*3], a1_ = x1w[t*3+1], a2_ = x1w[t*3+2];
        sv0[t] = fmaf(a0_, t3[0][0], fmaf(a1_, t3[0][1], a2_*t3[0][2]));
        sv1[t] = fmaf(a0_, t3[1][0], fmaf(a1_, t3[1][1], a2_*t3[1][2]));
        sv2[t] = fmaf(a0_, t3[2][0], fmaf(a1_, t3[2][1], a2_*t3[2][2]));
      }
      const short8 a0 = mkfrag(sv0), a1 = mkfrag(sv1), a2 = mkfrag(sv2);
      acc[0][0] = MFMA(a0, bf0, acc[0][0]);
      acc[0][1] = MFMA(a0, bf1, acc[0][1]);
      acc[1][0] = MFMA(a1, bf0, acc[1][0]);
      acc[1][1] = MFMA(a1, bf1, acc[1][1]);
      acc[2][0] = MFMA(a2, bf0, acc[2][0]);
      acc[2][1] = MFMA(a2, bf1, acc[2][1]);
    }
    // --- 2-way K reduction + store (3 consecutive floats per (b,w)) ---
    __syncthreads();
    float* red = reinterpret_cast<float*>(lxh);
    if (kh == 1){
      #pragma unroll
      for (int k3 = 0; k3 < 3; ++k3)
        #pragma unroll
        for (int nt = 0; nt < 2; ++nt)
          #pragma unroll
          for (int r = 0; r < 4; ++r)
            red[mq*1536 + (k3*2 + nt)*256 + (tg*4 + r)*16 + col] = acc[k3][nt][r];
    }
    __syncthreads();
    if (kh == 0){
      #pragma unroll
      for (int r = 0; r < 4; ++r){
        const int b = b0 + mq*16 + tg*4 + r;
        if (b < 20000){
          #pragma unroll
          for (int nt = 0; nt < 2; ++nt){
            const int w2 = nt*16 + col;
            float* o = out + (size_t)b*240 + 64 + 3*w2;
            #pragma unroll
            for (int k3 = 0; k3 < 3; ++k3)
              o[k3] = acc[k3][nt][r]
                    + red[mq*1536 + (k3*2 + nt)*256 + (tg*4 + r)*16 + col];
          }
        }
      }
    }

  } else {
    // ===== GEMM 2: out[:,160:240] (w*5+k), K=2304, 4-way M (mq) x 2-way K =====
    const unsigned short* bpl = wt + WT2_OFF + fo;
    const int mq = wv >> 1;
    const int kh = wv & 1;
    const unsigned short* rb = &lxh[(mq*16 + col)*XSH];

    float4v acc[5] = { z4, z4, z4, z4, z4 };

    float w8[8];
    ldw<8>(rb + kh*32 + tg*8, w8);
    float x1w[24];
    ldw<24>(rb + 64 + tg*24, x1w);

    // --- (0,2,2)+(2,0,2) folded: s in [0,32), K=v2*64+u0 ---
    for (int s = kh; s < 32; s += 2){
      const short8 bf = ldB(bpl + s*512);
      const int v2 = s >> 1;
      float xq[5];
      #pragma unroll
      for (int j = 0; j < 5; ++j) xq[j] = bf2f(rb[160 + v2*5 + j]);
      float sv[5][8];
      #pragma unroll
      for (int t = 0; t < 8; ++t){
        const float xw = w8[t];
        #pragma unroll
        for (int k5 = 0; k5 < 5; ++k5) sv[k5][t] = xw * xq[k5];
      }
      #pragma unroll
      for (int k5 = 0; k5 < 5; ++k5) acc[k5] = MFMA(mkfrag(sv[k5]), bf, acc[k5]);
    }
    // --- (1,1,2): s in [32,64), K=u*32+v, precontracted ---
    for (int s = 32 + kh; s < 64; s += 2){
      const short8 bf = ldB(bpl + s*512);
      const int u = s - 32;
      float xu[3];
      #pragma unroll
      for (int i = 0; i < 3; ++i) xu[i] = bf2f(rb[64 + u*3 + i]);
      // t5[kk][j] = sum_i C112[i][j][kk] * xu[i]
      float t5[5][3];
      #pragma unroll
      for (int kk = 0; kk < 5; ++kk)
        #pragma unroll
        for (int j = 0; j < 3; ++j){
          float a = 0.f;
          #pragma unroll
          for (int i = 0; i < 3; ++i){
            const double cd = T112.v[i][j][kk];
            if (NZ(cd)) a = fmaf((float)cd, xu[i], a);
          }
          t5[kk][j] = a;
        }
      float sv[5][8];
      #pragma unroll
      for (int t = 0; t < 8; ++t){
        const float b0_ = x1w[t*3], b1_ = x1w[t*3+1], b2_ = x1w[t*3+2];
        #pragma unroll
        for (int kk = 0; kk < 5; ++kk)
          sv[kk][t] = fmaf(b0_, t5[kk][0], fmaf(b1_, t5[kk][1], b2_*t5[kk][2]));
      }
      #pragma unroll
      for (int k5 = 0; k5 < 5; ++k5) acc[k5] = MFMA(mkfrag(sv[k5]), bf, acc[k5]);
    }
    // --- (2,2,2): s in [64,72), K=u*16+v, precontracted per-lane ---
    {
      float x2w[40];
      ldw<40>(rb + 160 + (tg&1)*40, x2w);
      for (int s = 64 + kh; s < 72; s += 2){
        const short8 bf = ldB(bpl + s*512);
        const int ub = (s - 64)*2 + (tg >> 1);
        float xu[5];
        #pragma unroll
        for (int i = 0; i < 5; ++i) xu[i] = bf2f(rb[160 + ub*5 + i]);
        // t5[kk][j] = sum_i C222[i][j][kk] * xu[i]
        float t5[5][5];
        #pragma unroll
        for (int kk = 0; kk < 5; ++kk)
          #pragma unroll
          for (int j = 0; j < 5; ++j){
            float a = 0.f;
            #pragma unroll
            for (int i = 0; i < 5; ++i){
              const double cd = T222.v[i][j][kk];
              if (NZ(cd)) a = fmaf((float)cd, xu[i], a);
            }
            t5[kk][j] = a;
          }
        float sv[5][8];
        #pragma unroll
        for (int t = 0; t < 8; ++t){
          #pragma unroll
          for (int kk = 0; kk < 5; ++kk){
            float a = 0.f;
            #pragma unroll
            for (int j = 0; j < 5; ++j) a = fmaf(x2w[t*5+j], t5[kk][j], a);
            sv[kk][t] = a;
          }
        }
        #pragma unroll
        for (int k5 = 0; k5 < 5; ++k5) acc[k5] = MFMA(mkfrag(sv[k5]), bf, acc[k5]);
      }
    }
    // --- 2-way K reduction + store (5 consecutive floats per (b,w)) ---
    __syncthreads();
    float* red = reinterpret_cast<float*>(lxh);
    if (kh == 1){
      #pragma unroll
      for (int k5 = 0; k5 < 5; ++k5)
        #pragma unroll
        for (int r = 0; r < 4; ++r)
          red[mq*1280 + k5*256 + (tg*4 + r)*16 + col] = acc[k5][r];
    }
    __syncthreads();
    if (kh == 0){
      #pragma unroll
      for (int r = 0; r < 4; ++r){
        const int b = b0 + mq*16 + tg*4 + r;
        if (b < 20000){
          float* o = out + (size_t)b*240 + 160 + 5*col;
          #pragma unroll
          for (int k5 = 0; k5 < 5; ++k5)
            o[k5] = acc[k5][r] + red[mq*1280 + k5*256 + (tg*4 + r)*16 + col];
        }
      }
    }
  }
}

// ---------------------------------------------------------------------------
extern "C" void kernel_launch(void* const* d_in, const int* in_sizes, int n_in,
                              void* d_out, int out_size, void* d_ws, size_t ws_size,
                              hipStream_t stream){
  (void)in_sizes; (void)n_in; (void)out_size; (void)ws_size;
  const float* x = (const float*)d_in[0];
  const float* w[11];
  for (int i = 0; i < 11; ++i) w[i] = (const float*)d_in[1 + i];
  unsigned short* wt = (unsigned short*)d_ws;
  float* out = (float*)d_out;

  dim3 gp(136, 3);
  tsq_prep<<<gp, 256, 0, stream>>>(w[0], w[1], w[2], w[3], w[4], w[5],
                                   w[6], w[7], w[8], w[9], w[10], wt);
  dim3 gm(3, 313);
  tsq_main<<<gm, 512, 0, stream>>>(x, wt, out);
}

// Round 9
// 165.000 us; speedup vs baseline: 1.5195x; 1.5195x over previous
//
#include <hip/hip_runtime.h>
#include <stdint.h>
#include <stddef.h>

// ============================================================================
// HTensorSquare: out[b] = sum_paths alpha * einsum(uvw,ijk,bui,bvj->bwk)
// Irreps in/out: 64x0e + 32x1o + 16x2e  (DIM 240), B = 20000.
// Fused into 3 GEMMs, A-operand generated in registers, B = preprocessed bf16
// weights in MFMA-fragment tile order.  K folded by x@x symmetry (round 7).
// Round-9: round-8's bf16 x-tile (31.7 KB LDS) with the register budget fixed:
//   - __launch_bounds__(512, 4)  [round 8's (512,6) forced VGPR=40 -> massive
//     scratch spills, WRITE_SIZE 31->145 MB, 2x slowdown]
//   - xv[40] window reloaded per-mt inside the (2,2,0) loop (round-7
//     structure) instead of hoisted 2x40 f32 -> keeps live set ~64 VGPR.
// ============================================================================

// ---------------------------------------------------------------------------
// Compile-time Clebsch-Gordan machinery (exact port of the reference numpy).
// ---------------------------------------------------------------------------
namespace cg {

struct Cx { double re, im; };
constexpr Cx cmul(Cx a, Cx b){ return { a.re*b.re - a.im*b.im, a.re*b.im + a.im*b.re }; }

constexpr double fact(int n){ double r = 1.0; for (int i = 2; i <= n; ++i) r *= (double)i; return r; }

constexpr double csqrt(double x){
  if (x <= 0.0) return 0.0;
  double r = x > 1.0 ? x : 1.0;
  for (int i = 0; i < 50; ++i) r = 0.5*(r + x/r);
  return r;
}

constexpr double neg1pow(int k){ return (k % 2 == 0) ? 1.0 : -1.0; }

constexpr double su2_cg(int j1,int m1,int j2,int m2,int j3,int m3){
  if (m3 != m1 + m2) return 0.0;
  int vmin = -j1 + j2 + m3;
  if (-j1 + m1 > vmin) vmin = -j1 + m1;
  if (0 > vmin) vmin = 0;
  int vmax = j2 + j3 + m1;
  if (j3 - j1 + j2 < vmax) vmax = j3 - j1 + j2;
  if (j3 + m3 < vmax) vmax = j3 + m3;
  if (vmax < vmin) return 0.0;
  double C = csqrt((2.0*j3 + 1.0)*fact(j3+j1-j2)*fact(j3-j1+j2)*fact(j1+j2-j3)
                   *fact(j3+m3)*fact(j3-m3)
                   /(fact(j1+j2+j3+1)*fact(j1-m1)*fact(j1+m1)*fact(j2-m2)*fact(j2+m2)));
  double S = 0.0;
  for (int v = vmin; v <= vmax; ++v)
    S += neg1pow(v + j2 + m2)*fact(j2+j3+m1-v)*fact(j1-m1+v)
       /(fact(v)*fact(j3-j1+j2-v)*fact(j3+m3-v)*fact(v+j1-j2-m3));
  return C*S;
}

struct QM { Cx v[5][5]; };
constexpr QM qmat(int l){
  QM q{};
  const double r2 = 0.70710678118654752440;
  for (int m = -l; m < 0; ++m){
    q.v[l+m][l-m] = Cx{ r2, 0.0 };       // q[l+m, l+|m|]
    q.v[l+m][l+m] = Cx{ 0.0, -r2 };      // q[l+m, l-|m|]
  }
  q.v[l][l] = Cx{ 1.0, 0.0 };
  for (int m = 1; m <= l; ++m){
    double s = neg1pow(m)*r2;
    q.v[l+m][l+m] = Cx{ s, 0.0 };
    q.v[l+m][l-m] = Cx{ 0.0, s };
  }
  Cx ph = (l % 4 == 0) ? Cx{1,0} : (l % 4 == 1) ? Cx{0,-1} : (l % 4 == 2) ? Cx{-1,0} : Cx{0,1};
  QM out{};
  for (int i = 0; i < 5; ++i) for (int j = 0; j < 5; ++j) out.v[i][j] = cmul(ph, q.v[i][j]);
  return out;
}

struct CGT { double v[5][5][5]; };
// Real-basis CG * sqrt(2*l3+1)   (matches reference CGS entries)
constexpr CGT cg_tab(int l1,int l2,int l3){
  double C[5][5][5] = {};
  for (int m1 = -l1; m1 <= l1; ++m1)
    for (int m2 = -l2; m2 <= l2; ++m2)
      for (int m3 = -l3; m3 <= l3; ++m3)
        C[l1+m1][l2+m2][l3+m3] = su2_cg(l1,m1,l2,m2,l3,m3);
  QM Q1 = qmat(l1), Q2 = qmat(l2), Q3 = qmat(l3);
  const int n1 = 2*l1+1, n2 = 2*l2+1, n3 = 2*l3+1;
  const double norm = csqrt(2.0*l3 + 1.0);
  CGT R{};
  for (int j = 0; j < n1; ++j)
    for (int l = 0; l < n2; ++l)
      for (int m = 0; m < n3; ++m){
        Cx s{0,0};
        for (int i = 0; i < n1; ++i)
          for (int k = 0; k < n2; ++k)
            for (int n = 0; n < n3; ++n){
              double c = C[i][k][n];
              if (c != 0.0){
                Cx q3c{ Q3.v[n][m].re, -Q3.v[n][m].im };   // conj(Q3.T)[m][n]
                Cx t = cmul(cmul(Q1.v[i][j], Q2.v[k][l]), q3c);
                s.re += t.re*c; s.im += t.im*c;
              }
            }
        R.v[j][l][m] = s.re * norm;
      }
  return R;
}

constexpr double tab_sumsq(const CGT& t, int n1, int n2, int n3){
  double s = 0;
  for (int i = 0; i < n1; ++i) for (int j = 0; j < n2; ++j) for (int k = 0; k < n3; ++k)
    s += t.v[i][j][k]*t.v[i][j][k];
  return s;
}

} // namespace cg

// Full tables for the 4 non-trivial paths
constexpr cg::CGT T121 = cg::cg_tab(1,2,1);
constexpr cg::CGT T211 = cg::cg_tab(2,1,1);
constexpr cg::CGT T112 = cg::cg_tab(1,1,2);
constexpr cg::CGT T222 = cg::cg_tab(2,2,2);
// Scalar constants for delta-structured paths
constexpr double C000 = cg::cg_tab(0,0,0).v[0][0][0];
constexpr double C011 = cg::cg_tab(0,1,1).v[0][0][0];
constexpr double C022 = cg::cg_tab(0,2,2).v[0][0][0];
constexpr double C101 = cg::cg_tab(1,0,1).v[0][0][0];
constexpr double C110 = cg::cg_tab(1,1,0).v[0][0][0];
constexpr double C220 = cg::cg_tab(2,2,0).v[0][0][0];
constexpr double C202 = cg::cg_tab(2,0,2).v[0][0][0];

// Sanity checks
static_assert(C000 > 0.99 && C000 < 1.01, "C000");
static_assert(C011 > 1.72 && C011 < 1.74, "C011");
static_assert(C101 > 1.72 && C101 < 1.74, "C101");
static_assert(C022 > 2.22 && C022 < 2.25, "C022");
static_assert(C202 > 2.22 && C202 < 2.25, "C202");
static_assert(C110*C110 > 0.332 && C110*C110 < 0.334, "C110");
static_assert(C220*C220 > 0.199 && C220*C220 < 0.201, "C220");
static_assert(cg::tab_sumsq(T121,3,5,3) > 8.9  && cg::tab_sumsq(T121,3,5,3) < 9.1,  "T121");
static_assert(cg::tab_sumsq(T211,5,3,3) > 8.9  && cg::tab_sumsq(T211,5,3,3) < 9.1,  "T211");
static_assert(cg::tab_sumsq(T112,3,3,5) > 24.9 && cg::tab_sumsq(T112,3,3,5) < 25.1, "T112");
static_assert(cg::tab_sumsq(T222,5,5,5) > 24.9 && cg::tab_sumsq(T222,5,5,5) < 25.1, "T222");

// The (2,1,1)->(1,2,1) fold requires C211[i][j][k] == C121[j][i][k].
constexpr double t121_t211_swapdiff(){
  double m = 0;
  for (int i = 0; i < 5; ++i)
    for (int j = 0; j < 3; ++j)
      for (int k = 0; k < 3; ++k){
        double d = T211.v[i][j][k] - T121.v[j][i][k];
        if (d < 0) d = -d;
        if (d > m) m = d;
      }
  return m;
}
static_assert(t121_t211_swapdiff() < 1e-9, "T211 != T121^T -- fold invalid");

// Normalization (fan-in per output irrep) folded into weights.
constexpr double A0 = 1.0/cg::csqrt(5376.0);
constexpr double A1 = 1.0/cg::csqrt(5120.0);
constexpr double A2 = 1.0/cg::csqrt(3328.0);

constexpr double S000 = A0*C000, S110 = A0*C110, S220 = A0*C220;
constexpr double S011 = A1*C011, S101 = A1*C101, S121 = A1, S211 = A1;
constexpr double S022 = A2*C022, S112 = A2,      S202 = A2*C202, S222 = A2;

// Folded K extents (bf16 elements), fragment-tiled layout:
// element (n = nt*16+col, k = s*32+kk) at base_g + (s*NT_g + nt)*512 + col*32 + kk.
constexpr int K0 = 4352, K1 = 2560, K2 = 2304;   // S0=136, S1=80, S2=72
constexpr int WT1_OFF = 64*K0;              // 278528
constexpr int WT2_OFF = WT1_OFF + 32*K1;    // 360448

// ---------------------------------------------------------------------------
// Device helpers
// ---------------------------------------------------------------------------
using short8  = __attribute__((ext_vector_type(8))) short;
using float4v = __attribute__((ext_vector_type(4))) float;

// RNE pack of two f32 -> packed 2x bf16 (one v_cvt_pk_bf16_f32).
__device__ __forceinline__ unsigned pkbf(float lo, float hi){
  unsigned r;
  asm("v_cvt_pk_bf16_f32 %0, %1, %2" : "=v"(r) : "v"(lo), "v"(hi));
  return r;
}

__device__ __forceinline__ short8 mkfrag(const float* s){
  union { short8 v; unsigned u[4]; } f;
  f.u[0] = pkbf(s[0], s[1]);
  f.u[1] = pkbf(s[2], s[3]);
  f.u[2] = pkbf(s[4], s[5]);
  f.u[3] = pkbf(s[6], s[7]);
  return f.v;
}

__device__ __forceinline__ short8 ldB(const unsigned short* p){
  return *reinterpret_cast<const short8*>(p);   // global_load_dwordx4
}

__device__ __forceinline__ float4v MFMA(short8 a, short8 b, float4v c){
  return __builtin_amdgcn_mfma_f32_16x16x32_bf16(a, b, c, 0, 0, 0);
}

__device__ __forceinline__ unsigned short f2bf_rne(float f){
  unsigned u = __builtin_bit_cast(unsigned, f);
  u += 0x7fffu + ((u >> 16) & 1u);
  return (unsigned short)(u >> 16);
}

// bf16 (LDS) -> f32: one shift.
__device__ __forceinline__ float bf2f(unsigned short h){
  return __builtin_bit_cast(float, (unsigned)h << 16);
}

// Load N consecutive bf16 from LDS (16B-aligned, N multiple of 8) -> f32 regs.
template<int N>
__device__ __forceinline__ void ldw(const unsigned short* p, float* dst){
  #pragma unroll
  for (int q = 0; q < N/8; ++q){
    union { short8 v; unsigned short u[8]; } t;
    t.v = *reinterpret_cast<const short8*>(p + q*8);
    #pragma unroll
    for (int i = 0; i < 8; ++i) dst[q*8 + i] = bf2f(t.u[i]);
  }
}

#define NZ(c) ((c) > 1e-12 || (c) < -1e-12)

constexpr int XSH = 248;  // x-tile LDS row stride (ushorts): 496B, 2-way banks

// ---------------------------------------------------------------------------
// Weight preprocessing v3: folded + fragment-tiled (identical to round 7).
// grid (136, 3), block 256.
// ---------------------------------------------------------------------------
__global__ __launch_bounds__(256)
void tsq_prep(const float* __restrict__ w0, const float* __restrict__ w1,
              const float* __restrict__ w2, const float* __restrict__ w3,
              const float* __restrict__ w4, const float* __restrict__ w5,
              const float* __restrict__ w6, const float* __restrict__ w7,
              const float* __restrict__ w8, const float* __restrict__ w9,
              const float* __restrict__ w10, unsigned short* __restrict__ wt){
  const int s   = blockIdx.x;
  const int g   = blockIdx.y;
  const int tid = threadIdx.x;

  const int lw  = 6 - g;                 // log2(Wn): 6,5,4
  const int Wn  = 1 << lw;               // 64,32,16
  const int NT  = Wn >> 4;               // 4,2,1
  int Smax;
  unsigned short* obase;
  if (g == 0){ Smax = 136; obase = wt; }
  else if (g == 1){ Smax = 80; obase = wt + WT1_OFF; }
  else { Smax = 72; obase = wt + WT2_OFF; }
  if (s >= Smax) return;

  __shared__ unsigned short tl[32*66];   // max 32 x (64+2)
  const int st = Wn + 2;

  // ---- phase 1: gather/scale/convert (with mirror folds), coalesced in n ----
  const int nel = 32 << lw;              // == NT*512
  for (int idx = tid; idx < nel; idx += 256){
    const int kk = idx >> lw, n = idx & (Wn - 1);
    float v;
    if (g == 0){
      if (s < 64){                                   // (0,0,0) u<32, all v
        const int u = s >> 1, vv = (s & 1)*32 + kk;
        v = w0[(u*64 + vv)*64 + n];
        if (s & 1) v += w0[(vv*64 + u)*64 + n];      // fold dropped (u>=32,v<32)
        v *= (float)S000;
      } else if (s < 96){                            // (0,0,0) u>=32, v>=32
        const int u = s - 32, vv = 32 + kk;
        v = w0[(u*64 + vv)*64 + n] * (float)S000;
      } else if (s < 128){                           // (1,1,0) K=u*32+v
        v = w4[((s-96)*32 + kk)*64 + n] * (float)S110;
      } else {                                       // (2,2,0) K=u*16+v
        v = w9[((s-128)*32 + kk)*64 + n] * (float)S220;
      }
    } else if (g == 1){
      const int k = s*32 + kk;
      if (s < 64){                                   // (0,1,1)+(1,0,1), K=A1*64+A0
        v = w1[((k&63)*32 + (k>>6))*32 + n] * (float)S011
          + w3[k*32 + n] * (float)S101;
      } else {                                       // (1,2,1)+(2,1,1), K=v2*32+u1
        const int kr = k - 2048;
        const int u1 = kr & 31, v2 = kr >> 5;
        v = w6[(u1*16 + v2)*32 + n] * (float)S121
          + w8[(v2*32 + u1)*32 + n] * (float)S211;
      }
    } else {
      const int k = s*32 + kk;
      if (s < 32){                                   // (0,2,2)+(2,0,2), K=v2*64+u0
        v = w2[((k&63)*16 + (k>>6))*16 + n] * (float)S022
          + w7[k*16 + n] * (float)S202;
      } else if (s < 64){                            // (1,1,2) K=u*32+v
        v = w5[(k-1024)*16 + n] * (float)S112;
      } else {                                       // (2,2,2) K=u*16+v
        v = w10[(k-2048)*16 + n] * (float)S222;
      }
    }
    tl[kk*st + n] = f2bf_rne(v);
  }
  __syncthreads();

  // ---- phase 2: contiguous fragment-order write ----
  unsigned short* o = obase + (size_t)s*NT*512;
  const int nout = NT*512;
  for (int idx = tid; idx < nout; idx += 256){
    const int nt  = idx >> 9;
    const int r   = idx & 511;
    const int col = r >> 5;
    const int kk  = r & 31;
    o[idx] = tl[kk*st + nt*16 + col];
  }
}

// ---------------------------------------------------------------------------
// Main kernel.  grid (3, 313), block 512 (8 waves).  blockIdx.x = GEMM id,
// blockIdx.y = batch tile of 64 rows.  x tile staged in LDS as bf16 (RNE):
// 64 x 248 ushorts = 31.7 KB -> up to 4 blocks/CU at VGPR<=64 (was 2).
// Reduction scratch reuses the x LDS as f32 (7936 floats); GEMM0 = 3 passes.
// __launch_bounds__(512,4): VGPR cap 128.  (512,6) forced VGPR=40 -> spills.
// ---------------------------------------------------------------------------
__global__ __launch_bounds__(512, 4)
void tsq_main(const float* __restrict__ x, const unsigned short* __restrict__ wt,
              float* __restrict__ out){
  __shared__ unsigned short lxh[64*XSH];
  const int g    = blockIdx.x;
  const int b0   = blockIdx.y * 64;
  const int tid  = threadIdx.x;
  const int wv   = tid >> 6;      // 0..7
  const int lane = tid & 63;
  const int col  = lane & 15;
  const int tg   = lane >> 4;
  const int fo   = col*32 + tg*8; // per-lane fragment offset within a 512-el tile

  // ---- stage x tile: f32 global -> RNE bf16 LDS (uint2 = 4 elems / store) ----
  for (int i = tid; i < 64*60; i += 512){
    const int r = i / 60, c = i - r*60;
    int gb = b0 + r; if (gb > 19999) gb = 19999;
    const float4 v = *(reinterpret_cast<const float4*>(x + (size_t)gb*240) + c);
    uint2 p; p.x = pkbf(v.x, v.y); p.y = pkbf(v.z, v.w);
    *reinterpret_cast<uint2*>(&lxh[r*XSH + c*4]) = p;
  }
  __syncthreads();

  const float4v z4 = {0.f, 0.f, 0.f, 0.f};

  if (g == 0){
    // ====== GEMM 0: out[:,0:64], K=4352, 2-way M (mh) x 4-way K (kh) ======
    const unsigned short* bpl = wt + fo;
    const int mh  = wv >> 2;
    const int kh  = wv & 3;
    const int par = kh & 1;       // s-parity for s<64 (constant per wave)

    float4v acc[2][4];
    #pragma unroll
    for (int mt = 0; mt < 2; ++mt)
      #pragma unroll
      for (int nt = 0; nt < 4; ++nt) acc[mt][nt] = z4;

    const unsigned short* rbase[2];
    #pragma unroll
    for (int mt = 0; mt < 2; ++mt) rbase[mt] = &lxh[(mh*32 + mt*16 + col)*XSH];

    // wA = x0 window for parity `par` (s<64); wB = x0 upper half (s>=64).
    float wA[2][8], wB[2][8];
    #pragma unroll
    for (int mt = 0; mt < 2; ++mt){
      ldw<8>(rbase[mt] + par*32 + tg*8, wA[mt]);
      ldw<8>(rbase[mt] + 32 + tg*8,     wB[mt]);
    }

    // --- (0,0,0) part A: s in [0,64), u = s>>1 (<32), window = wA ---
    for (int s = kh; s < 64; s += 4){
      short8 bf[4];
      #pragma unroll
      for (int nt = 0; nt < 4; ++nt) bf[nt] = ldB(bpl + (s*4 + nt)*512);
      const int u = s >> 1;
      #pragma unroll
      for (int mt = 0; mt < 2; ++mt){
        const float xu = bf2f(rbase[mt][u]);
        float sv[8];
        #pragma unroll
        for (int t = 0; t < 8; ++t) sv[t] = xu * wA[mt][t];
        const short8 af = mkfrag(sv);
        #pragma unroll
        for (int nt = 0; nt < 4; ++nt) acc[mt][nt] = MFMA(af, bf[nt], acc[mt][nt]);
      }
    }
    // --- (0,0,0) part B: s in [64,96), u = s-32 (>=32), window = wB ---
    for (int s = 64 + kh; s < 96; s += 4){
      short8 bf[4];
      #pragma unroll
      for (int nt = 0; nt < 4; ++nt) bf[nt] = ldB(bpl + (s*4 + nt)*512);
      const int u = s - 32;
      #pragma unroll
      for (int mt = 0; mt < 2; ++mt){
        const float xu = bf2f(rbase[mt][u]);
        float sv[8];
        #pragma unroll
        for (int t = 0; t < 8; ++t) sv[t] = xu * wB[mt][t];
        const short8 af = mkfrag(sv);
        #pragma unroll
        for (int nt = 0; nt < 4; ++nt) acc[mt][nt] = MFMA(af, bf[nt], acc[mt][nt]);
      }
    }
    // --- (1,1,0): s in [96,128), u = s-96, K=u*32+v ---
    float x1w[2][24];
    #pragma unroll
    for (int mt = 0; mt < 2; ++mt) ldw<24>(rbase[mt] + 64 + tg*24, x1w[mt]);
    for (int s = 96 + kh; s < 128; s += 4){
      short8 bf[4];
      #pragma unroll
      for (int nt = 0; nt < 4; ++nt) bf[nt] = ldB(bpl + (s*4 + nt)*512);
      const int u = s - 96;
      #pragma unroll
      for (int mt = 0; mt < 2; ++mt){
        const unsigned short* rb = rbase[mt];
        const float u0 = bf2f(rb[64+u*3]), u1 = bf2f(rb[64+u*3+1]), u2 = bf2f(rb[64+u*3+2]);
        float sv[8];
        #pragma unroll
        for (int t = 0; t < 8; ++t)
          sv[t] = fmaf(u0, x1w[mt][t*3], fmaf(u1, x1w[mt][t*3+1], u2*x1w[mt][t*3+2]));
        const short8 af = mkfrag(sv);
        #pragma unroll
        for (int nt = 0; nt < 4; ++nt) acc[mt][nt] = MFMA(af, bf[nt], acc[mt][nt]);
      }
    }
    // --- (2,2,0): s in [128,136), K=u*16+v (xv reloaded per mt: low VGPR) ---
    for (int s = 128 + kh; s < 136; s += 4){
      short8 bf[4];
      #pragma unroll
      for (int nt = 0; nt < 4; ++nt) bf[nt] = ldB(bpl + (s*4 + nt)*512);
      const int ub = (s - 128)*2 + (tg >> 1);
      #pragma unroll
      for (int mt = 0; mt < 2; ++mt){
        const unsigned short* rb = rbase[mt];
        float xu[5];
        #pragma unroll
        for (int i = 0; i < 5; ++i) xu[i] = bf2f(rb[160 + ub*5 + i]);
        float xv[40];
        ldw<40>(rb + 160 + (tg&1)*40, xv);
        float sv[8];
        #pragma unroll
        for (int t = 0; t < 8; ++t){
          float a = 0.f;
          #pragma unroll
          for (int i = 0; i < 5; ++i) a = fmaf(xu[i], xv[t*5+i], a);
          sv[t] = a;
        }
        const short8 af = mkfrag(sv);
        #pragma unroll
        for (int nt = 0; nt < 4; ++nt) acc[mt][nt] = MFMA(af, bf[nt], acc[mt][nt]);
      }
    }
    // --- 4-way K reduction, 3 passes of 16 KB (scratch = lxh as f32) ---
    __syncthreads();
    float* red = reinterpret_cast<float*>(lxh);
    #pragma unroll
    for (int p = 1; p <= 3; ++p){
      if (kh == p){
        #pragma unroll
        for (int mt = 0; mt < 2; ++mt)
          #pragma unroll
          for (int nt = 0; nt < 4; ++nt)
            #pragma unroll
            for (int r = 0; r < 4; ++r)
              red[mh*2048 + (mt*4 + nt)*256 + (tg*4 + r)*16 + col] = acc[mt][nt][r];
      }
      __syncthreads();
      if (kh == 0){
        #pragma unroll
        for (int mt = 0; mt < 2; ++mt)
          #pragma unroll
          for (int nt = 0; nt < 4; ++nt)
            #pragma unroll
            for (int r = 0; r < 4; ++r)
              acc[mt][nt][r] += red[mh*2048 + (mt*4 + nt)*256 + (tg*4 + r)*16 + col];
      }
      __syncthreads();
    }
    if (kh == 0){
      #pragma unroll
      for (int mt = 0; mt < 2; ++mt)
        #pragma unroll
        for (int r = 0; r < 4; ++r){
          const int b = b0 + mh*32 + mt*16 + tg*4 + r;
          if (b < 20000){
            #pragma unroll
            for (int nt = 0; nt < 4; ++nt)
              out[(size_t)b*240 + nt*16 + col] = acc[mt][nt][r];
          }
        }
    }

  } else if (g == 1){
    // ===== GEMM 1: out[:,64:160] (w*3+k), K=2560, 4-way M (mq) x 2-way K =====
    const unsigned short* bpl = wt + WT1_OFF + fo;
    const int mq = wv >> 1;
    const int kh = wv & 1;
    const unsigned short* rb = &lxh[(mq*16 + col)*XSH];

    float4v acc[3][2];
    #pragma unroll
    for (int k3 = 0; k3 < 3; ++k3)
      #pragma unroll
      for (int nt = 0; nt < 2; ++nt) acc[k3][nt] = z4;

    float w8[8];
    ldw<8>(rb + kh*32 + tg*8, w8);
    float x1w[24];
    ldw<24>(rb + 64 + tg*24, x1w);

    // --- (0,1,1)+(1,0,1) folded: s in [0,64), K=A1*64+A0 ---
    for (int s = kh; s < 64; s += 2){
      const short8 bf0 = ldB(bpl + (s*2    )*512);
      const short8 bf1 = ldB(bpl + (s*2 + 1)*512);
      const int m = s >> 1;
      const float c0 = bf2f(rb[64+m*3]), c1 = bf2f(rb[64+m*3+1]), c2 = bf2f(rb[64+m*3+2]);
      float sv0[8], sv1[8], sv2[8];
      #pragma unroll
      for (int t = 0; t < 8; ++t){
        const float xw = w8[t];
        sv0[t] = xw*c0; sv1[t] = xw*c1; sv2[t] = xw*c2;
      }
      const short8 a0 = mkfrag(sv0), a1 = mkfrag(sv1), a2 = mkfrag(sv2);
      acc[0][0] = MFMA(a0, bf0, acc[0][0]);
      acc[0][1] = MFMA(a0, bf1, acc[0][1]);
      acc[1][0] = MFMA(a1, bf0, acc[1][0]);
      acc[1][1] = MFMA(a1, bf1, acc[1][1]);
      acc[2][0] = MFMA(a2, bf0, acc[2][0]);
      acc[2][1] = MFMA(a2, bf1, acc[2][1]);
    }
    // --- (1,2,1)+(2,1,1) folded: s in [64,80), K=v2*32+u1, precontracted ---
    for (int s = 64 + kh; s < 80; s += 2){
      const short8 bf0 = ldB(bpl + (s*2    )*512);
      const short8 bf1 = ldB(bpl + (s*2 + 1)*512);
      const int v2 = s - 64;
      float xq[5];
      #pragma unroll
      for (int j = 0; j < 5; ++j) xq[j] = bf2f(rb[160 + v2*5 + j]);
      // t3[kk][i] = sum_j C121[i][j][kk] * xq[j]
      float t3[3][3];
      #pragma unroll
      for (int kk = 0; kk < 3; ++kk)
        #pragma unroll
        for (int i = 0; i < 3; ++i){
          float a = 0.f;
          #pragma unroll
          for (int j = 0; j < 5; ++j){
            const double cd = T121.v[i][j][kk];
            if (NZ(cd)) a = fmaf((float)cd, xq[j], a);
          }
          t3[kk][i] = a;
        }
      float sv0[8], sv1[8], sv2[8];
      #pragma unroll
      for (int t = 0; t < 8; ++t){
        const float a0_ = x1w[t*3], a1_ = x1w[t*3+1], a2_ = x1w[t*3+2];
        sv0[t] = fmaf(a0_, t3[0][0], fmaf(a1_, t3[0][1], a2_*t3[0][2]));
        sv1[t] = fmaf(a0_, t3[1][0], fmaf(a1_, t3[1][1], a2_*t3[1][2]));
        sv2[t] = fmaf(a0_, t3[2][0], fmaf(a1_, t3[2][1], a2_*t3[2][2]));
      }
      const short8 a0 = mkfrag(sv0), a1 = mkfrag(sv1), a2 = mkfrag(sv2);
      acc[0][0] = MFMA(a0, bf0, acc[0][0]);
      acc[0][1] = MFMA(a0, bf1, acc[0][1]);
      acc[1][0] = MFMA(a1, bf0, acc[1][0]);
      acc[1][1] = MFMA(a1, bf1, acc[1][1]);
      acc[2][0] = MFMA(a2, bf0, acc[2][0]);
      acc[2][1] = MFMA(a2, bf1, acc[2][1]);
    }
    // --- 2-way K reduction + store (3 consecutive floats per (b,w)) ---
    __syncthreads();
    float* red = reinterpret_cast<float*>(lxh);
    if (kh == 1){
      #pragma unroll
      for (int k3 = 0; k3 < 3; ++k3)
        #pragma unroll
        for (int nt = 0; nt < 2; ++nt)
          #pragma unroll
          for (int r = 0; r < 4; ++r)
            red[mq*1536 + (k3*2 + nt)*256 + (tg*4 + r)*16 + col] = acc[k3][nt][r];
    }
    __syncthreads();
    if (kh == 0){
      #pragma unroll
      for (int r = 0; r < 4; ++r){
        const int b = b0 + mq*16 + tg*4 + r;
        if (b < 20000){
          #pragma unroll
          for (int nt = 0; nt < 2; ++nt){
            const int w2 = nt*16 + col;
            float* o = out + (size_t)b*240 + 64 + 3*w2;
            #pragma unroll
            for (int k3 = 0; k3 < 3; ++k3)
              o[k3] = acc[k3][nt][r]
                    + red[mq*1536 + (k3*2 + nt)*256 + (tg*4 + r)*16 + col];
          }
        }
      }
    }

  } else {
    // ===== GEMM 2: out[:,160:240] (w*5+k), K=2304, 4-way M (mq) x 2-way K =====
    const unsigned short* bpl = wt + WT2_OFF + fo;
    const int mq = wv >> 1;
    const int kh = wv & 1;
    const unsigned short* rb = &lxh[(mq*16 + col)*XSH];

    float4v acc[5] = { z4, z4, z4, z4, z4 };

    float w8[8];
    ldw<8>(rb + kh*32 + tg*8, w8);
    float x1w[24];
    ldw<24>(rb + 64 + tg*24, x1w);

    // --- (0,2,2)+(2,0,2) folded: s in [0,32), K=v2*64+u0 ---
    for (int s = kh; s < 32; s += 2){
      const short8 bf = ldB(bpl + s*512);
      const int v2 = s >> 1;
      float xq[5];
      #pragma unroll
      for (int j = 0; j < 5; ++j) xq[j] = bf2f(rb[160 + v2*5 + j]);
      float sv[5][8];
      #pragma unroll
      for (int t = 0; t < 8; ++t){
        const float xw = w8[t];
        #pragma unroll
        for (int k5 = 0; k5 < 5; ++k5) sv[k5][t] = xw * xq[k5];
      }
      #pragma unroll
      for (int k5 = 0; k5 < 5; ++k5) acc[k5] = MFMA(mkfrag(sv[k5]), bf, acc[k5]);
    }
    // --- (1,1,2): s in [32,64), K=u*32+v, precontracted ---
    for (int s = 32 + kh; s < 64; s += 2){
      const short8 bf = ldB(bpl + s*512);
      const int u = s - 32;
      float xu[3];
      #pragma unroll
      for (int i = 0; i < 3; ++i) xu[i] = bf2f(rb[64 + u*3 + i]);
      // t5[kk][j] = sum_i C112[i][j][kk] * xu[i]
      float t5[5][3];
      #pragma unroll
      for (int kk = 0; kk < 5; ++kk)
        #pragma unroll
        for (int j = 0; j < 3; ++j){
          float a = 0.f;
          #pragma unroll
          for (int i = 0; i < 3; ++i){
            const double cd = T112.v[i][j][kk];
            if (NZ(cd)) a = fmaf((float)cd, xu[i], a);
          }
          t5[kk][j] = a;
        }
      float sv[5][8];
      #pragma unroll
      for (int t = 0; t < 8; ++t){
        const float b0_ = x1w[t*3], b1_ = x1w[t*3+1], b2_ = x1w[t*3+2];
        #pragma unroll
        for (int kk = 0; kk < 5; ++kk)
          sv[kk][t] = fmaf(b0_, t5[kk][0], fmaf(b1_, t5[kk][1], b2_*t5[kk][2]));
      }
      #pragma unroll
      for (int k5 = 0; k5 < 5; ++k5) acc[k5] = MFMA(mkfrag(sv[k5]), bf, acc[k5]);
    }
    // --- (2,2,2): s in [64,72), K=u*16+v, precontracted per-lane ---
    {
      float x2w[40];
      ldw<40>(rb + 160 + (tg&1)*40, x2w);
      for (int s = 64 + kh; s < 72; s += 2){
        const short8 bf = ldB(bpl + s*512);
        const int ub = (s - 64)*2 + (tg >> 1);
        float xu[5];
        #pragma unroll
        for (int i = 0; i < 5; ++i) xu[i] = bf2f(rb[160 + ub*5 + i]);
        // t5[kk][j] = sum_i C222[i][j][kk] * xu[i]
        float t5[5][5];
        #pragma unroll
        for (int kk = 0; kk < 5; ++kk)
          #pragma unroll
          for (int j = 0; j < 5; ++j){
            float a = 0.f;
            #pragma unroll
            for (int i = 0; i < 5; ++i){
              const double cd = T222.v[i][j][kk];
              if (NZ(cd)) a = fmaf((float)cd, xu[i], a);
            }
            t5[kk][j] = a;
          }
        float sv[5][8];
        #pragma unroll
        for (int t = 0; t < 8; ++t){
          #pragma unroll
          for (int kk = 0; kk < 5; ++kk){
            float a = 0.f;
            #pragma unroll
            for (int j = 0; j < 5; ++j) a = fmaf(x2w[t*5+j], t5[kk][j], a);
            sv[kk][t] = a;
          }
        }
        #pragma unroll
        for (int k5 = 0; k5 < 5; ++k5) acc[k5] = MFMA(mkfrag(sv[k5]), bf, acc[k5]);
      }
    }
    // --- 2-way K reduction + store (5 consecutive floats per (b,w)) ---
    __syncthreads();
    float* red = reinterpret_cast<float*>(lxh);
    if (kh == 1){
      #pragma unroll
      for (int k5 = 0; k5 < 5; ++k5)
        #pragma unroll
        for (int r = 0; r < 4; ++r)
          red[mq*1280 + k5*256 + (tg*4 + r)*16 + col] = acc[k5][r];
    }
    __syncthreads();
    if (kh == 0){
      #pragma unroll
      for (int r = 0; r < 4; ++r){
        const int b = b0 + mq*16 + tg*4 + r;
        if (b < 20000){
          float* o = out + (size_t)b*240 + 160 + 5*col;
          #pragma unroll
          for (int k5 = 0; k5 < 5; ++k5)
            o[k5] = acc[k5][r] + red[mq*1280 + k5*256 + (tg*4 + r)*16 + col];
        }
      }
    }
  }
}

// ---------------------------------------------------------------------------
extern "C" void kernel_launch(void* const* d_in, const int* in_sizes, int n_in,
                              void* d_out, int out_size, void* d_ws, size_t ws_size,
                              hipStream_t stream){
  (void)in_sizes; (void)n_in; (void)out_size; (void)ws_size;
  const float* x = (const float*)d_in[0];
  const float* w[11];
  for (int i = 0; i < 11; ++i) w[i] = (const float*)d_in[1 + i];
  unsigned short* wt = (unsigned short*)d_ws;
  float* out = (float*)d_out;

  dim3 gp(136, 3);
  tsq_prep<<<gp, 256, 0, stream>>>(w[0], w[1], w[2], w[3], w[4], w[5],
                                   w[6], w[7], w[8], w[9], w[10], wt);
  dim3 gm(3, 313);
  tsq_main<<<gm, 512, 0, stream>>>(x, wt, out);
}

// Round 10
// 163.688 us; speedup vs baseline: 1.5317x; 1.0080x over previous
//
#include <hip/hip_runtime.h>
#include <stdint.h>
#include <stddef.h>

// ============================================================================
// HTensorSquare: out[b] = sum_paths alpha * einsum(uvw,ijk,bui,bvj->bwk)
// Irreps in/out: 64x0e + 32x1o + 16x2e  (DIM 240), B = 20000.
// Fused into 3 GEMMs, A-operand generated in registers, B = preprocessed bf16
// weights in MFMA-fragment tile order.  K folded by x@x symmetry (round 7);
// bf16 x-tile in LDS (round 9, 31.7 KB, VGPR=64 no spills).
// Round-10: PACKED-FP32 A-generation.  All sv-assembly loops rewritten as
// float2 vector ops (v_pk_mul_f32 / v_pk_fma_f32 on gfx950's full-rate packed
// FP32 pipe) -- halves the VALU issue count of the dominant A-gen stream.
// Windows pre-transposed into pair layout; CG precontraction stays scalar.
// Arithmetic is bit-identical to scalar f32 (same IEEE ops).
// ============================================================================

// ---------------------------------------------------------------------------
// Compile-time Clebsch-Gordan machinery (exact port of the reference numpy).
// ---------------------------------------------------------------------------
namespace cg {

struct Cx { double re, im; };
constexpr Cx cmul(Cx a, Cx b){ return { a.re*b.re - a.im*b.im, a.re*b.im + a.im*b.re }; }

constexpr double fact(int n){ double r = 1.0; for (int i = 2; i <= n; ++i) r *= (double)i; return r; }

constexpr double csqrt(double x){
  if (x <= 0.0) return 0.0;
  double r = x > 1.0 ? x : 1.0;
  for (int i = 0; i < 50; ++i) r = 0.5*(r + x/r);
  return r;
}

constexpr double neg1pow(int k){ return (k % 2 == 0) ? 1.0 : -1.0; }

constexpr double su2_cg(int j1,int m1,int j2,int m2,int j3,int m3){
  if (m3 != m1 + m2) return 0.0;
  int vmin = -j1 + j2 + m3;
  if (-j1 + m1 > vmin) vmin = -j1 + m1;
  if (0 > vmin) vmin = 0;
  int vmax = j2 + j3 + m1;
  if (j3 - j1 + j2 < vmax) vmax = j3 - j1 + j2;
  if (j3 + m3 < vmax) vmax = j3 + m3;
  if (vmax < vmin) return 0.0;
  double C = csqrt((2.0*j3 + 1.0)*fact(j3+j1-j2)*fact(j3-j1+j2)*fact(j1+j2-j3)
                   *fact(j3+m3)*fact(j3-m3)
                   /(fact(j1+j2+j3+1)*fact(j1-m1)*fact(j1+m1)*fact(j2-m2)*fact(j2+m2)));
  double S = 0.0;
  for (int v = vmin; v <= vmax; ++v)
    S += neg1pow(v + j2 + m2)*fact(j2+j3+m1-v)*fact(j1-m1+v)
       /(fact(v)*fact(j3-j1+j2-v)*fact(j3+m3-v)*fact(v+j1-j2-m3));
  return C*S;
}

struct QM { Cx v[5][5]; };
constexpr QM qmat(int l){
  QM q{};
  const double r2 = 0.70710678118654752440;
  for (int m = -l; m < 0; ++m){
    q.v[l+m][l-m] = Cx{ r2, 0.0 };       // q[l+m, l+|m|]
    q.v[l+m][l+m] = Cx{ 0.0, -r2 };      // q[l+m, l-|m|]
  }
  q.v[l][l] = Cx{ 1.0, 0.0 };
  for (int m = 1; m <= l; ++m){
    double s = neg1pow(m)*r2;
    q.v[l+m][l+m] = Cx{ s, 0.0 };
    q.v[l+m][l-m] = Cx{ 0.0, s };
  }
  Cx ph = (l % 4 == 0) ? Cx{1,0} : (l % 4 == 1) ? Cx{0,-1} : (l % 4 == 2) ? Cx{-1,0} : Cx{0,1};
  QM out{};
  for (int i = 0; i < 5; ++i) for (int j = 0; j < 5; ++j) out.v[i][j] = cmul(ph, q.v[i][j]);
  return out;
}

struct CGT { double v[5][5][5]; };
// Real-basis CG * sqrt(2*l3+1)   (matches reference CGS entries)
constexpr CGT cg_tab(int l1,int l2,int l3){
  double C[5][5][5] = {};
  for (int m1 = -l1; m1 <= l1; ++m1)
    for (int m2 = -l2; m2 <= l2; ++m2)
      for (int m3 = -l3; m3 <= l3; ++m3)
        C[l1+m1][l2+m2][l3+m3] = su2_cg(l1,m1,l2,m2,l3,m3);
  QM Q1 = qmat(l1), Q2 = qmat(l2), Q3 = qmat(l3);
  const int n1 = 2*l1+1, n2 = 2*l2+1, n3 = 2*l3+1;
  const double norm = csqrt(2.0*l3 + 1.0);
  CGT R{};
  for (int j = 0; j < n1; ++j)
    for (int l = 0; l < n2; ++l)
      for (int m = 0; m < n3; ++m){
        Cx s{0,0};
        for (int i = 0; i < n1; ++i)
          for (int k = 0; k < n2; ++k)
            for (int n = 0; n < n3; ++n){
              double c = C[i][k][n];
              if (c != 0.0){
                Cx q3c{ Q3.v[n][m].re, -Q3.v[n][m].im };   // conj(Q3.T)[m][n]
                Cx t = cmul(cmul(Q1.v[i][j], Q2.v[k][l]), q3c);
                s.re += t.re*c; s.im += t.im*c;
              }
            }
        R.v[j][l][m] = s.re * norm;
      }
  return R;
}

constexpr double tab_sumsq(const CGT& t, int n1, int n2, int n3){
  double s = 0;
  for (int i = 0; i < n1; ++i) for (int j = 0; j < n2; ++j) for (int k = 0; k < n3; ++k)
    s += t.v[i][j][k]*t.v[i][j][k];
  return s;
}

} // namespace cg

// Full tables for the 4 non-trivial paths
constexpr cg::CGT T121 = cg::cg_tab(1,2,1);
constexpr cg::CGT T211 = cg::cg_tab(2,1,1);
constexpr cg::CGT T112 = cg::cg_tab(1,1,2);
constexpr cg::CGT T222 = cg::cg_tab(2,2,2);
// Scalar constants for delta-structured paths
constexpr double C000 = cg::cg_tab(0,0,0).v[0][0][0];
constexpr double C011 = cg::cg_tab(0,1,1).v[0][0][0];
constexpr double C022 = cg::cg_tab(0,2,2).v[0][0][0];
constexpr double C101 = cg::cg_tab(1,0,1).v[0][0][0];
constexpr double C110 = cg::cg_tab(1,1,0).v[0][0][0];
constexpr double C220 = cg::cg_tab(2,2,0).v[0][0][0];
constexpr double C202 = cg::cg_tab(2,0,2).v[0][0][0];

// Sanity checks
static_assert(C000 > 0.99 && C000 < 1.01, "C000");
static_assert(C011 > 1.72 && C011 < 1.74, "C011");
static_assert(C101 > 1.72 && C101 < 1.74, "C101");
static_assert(C022 > 2.22 && C022 < 2.25, "C022");
static_assert(C202 > 2.22 && C202 < 2.25, "C202");
static_assert(C110*C110 > 0.332 && C110*C110 < 0.334, "C110");
static_assert(C220*C220 > 0.199 && C220*C220 < 0.201, "C220");
static_assert(cg::tab_sumsq(T121,3,5,3) > 8.9  && cg::tab_sumsq(T121,3,5,3) < 9.1,  "T121");
static_assert(cg::tab_sumsq(T211,5,3,3) > 8.9  && cg::tab_sumsq(T211,5,3,3) < 9.1,  "T211");
static_assert(cg::tab_sumsq(T112,3,3,5) > 24.9 && cg::tab_sumsq(T112,3,3,5) < 25.1, "T112");
static_assert(cg::tab_sumsq(T222,5,5,5) > 24.9 && cg::tab_sumsq(T222,5,5,5) < 25.1, "T222");

// The (2,1,1)->(1,2,1) fold requires C211[i][j][k] == C121[j][i][k].
constexpr double t121_t211_swapdiff(){
  double m = 0;
  for (int i = 0; i < 5; ++i)
    for (int j = 0; j < 3; ++j)
      for (int k = 0; k < 3; ++k){
        double d = T211.v[i][j][k] - T121.v[j][i][k];
        if (d < 0) d = -d;
        if (d > m) m = d;
      }
  return m;
}
static_assert(t121_t211_swapdiff() < 1e-9, "T211 != T121^T -- fold invalid");

// Normalization (fan-in per output irrep) folded into weights.
constexpr double A0 = 1.0/cg::csqrt(5376.0);
constexpr double A1 = 1.0/cg::csqrt(5120.0);
constexpr double A2 = 1.0/cg::csqrt(3328.0);

constexpr double S000 = A0*C000, S110 = A0*C110, S220 = A0*C220;
constexpr double S011 = A1*C011, S101 = A1*C101, S121 = A1, S211 = A1;
constexpr double S022 = A2*C022, S112 = A2,      S202 = A2*C202, S222 = A2;

// Folded K extents (bf16 elements), fragment-tiled layout:
// element (n = nt*16+col, k = s*32+kk) at base_g + (s*NT_g + nt)*512 + col*32 + kk.
constexpr int K0 = 4352, K1 = 2560, K2 = 2304;   // S0=136, S1=80, S2=72
constexpr int WT1_OFF = 64*K0;              // 278528
constexpr int WT2_OFF = WT1_OFF + 32*K1;    // 360448

// ---------------------------------------------------------------------------
// Device helpers
// ---------------------------------------------------------------------------
using short8  = __attribute__((ext_vector_type(8))) short;
using float4v = __attribute__((ext_vector_type(4))) float;
using float2v = __attribute__((ext_vector_type(2))) float;

// RNE pack of two f32 -> packed 2x bf16 (one v_cvt_pk_bf16_f32).
__device__ __forceinline__ unsigned pkbf(float lo, float hi){
  unsigned r;
  asm("v_cvt_pk_bf16_f32 %0, %1, %2" : "=v"(r) : "v"(lo), "v"(hi));
  return r;
}

// Fragment from 4 float2 pairs (pair q = elements 2q, 2q+1).
__device__ __forceinline__ short8 mkfrag2(const float2v* s){
  union { short8 v; unsigned u[4]; } f;
  f.u[0] = pkbf(s[0][0], s[0][1]);
  f.u[1] = pkbf(s[1][0], s[1][1]);
  f.u[2] = pkbf(s[2][0], s[2][1]);
  f.u[3] = pkbf(s[3][0], s[3][1]);
  return f.v;
}

__device__ __forceinline__ short8 ldB(const unsigned short* p){
  return *reinterpret_cast<const short8*>(p);   // global_load_dwordx4
}

__device__ __forceinline__ float4v MFMA(short8 a, short8 b, float4v c){
  return __builtin_amdgcn_mfma_f32_16x16x32_bf16(a, b, c, 0, 0, 0);
}

__device__ __forceinline__ unsigned short f2bf_rne(float f){
  unsigned u = __builtin_bit_cast(unsigned, f);
  u += 0x7fffu + ((u >> 16) & 1u);
  return (unsigned short)(u >> 16);
}

// bf16 (LDS) -> f32: one shift.
__device__ __forceinline__ float bf2f(unsigned short h){
  return __builtin_bit_cast(float, (unsigned)h << 16);
}

// Packed f32 helpers (backend selects v_pk_mul_f32 / v_pk_fma_f32 on gfx950).
__device__ __forceinline__ float2v b2(float x){ return (float2v){x, x}; }
__device__ __forceinline__ float2v pfma(float2v a, float2v b, float2v c){
#if __has_builtin(__builtin_elementwise_fma)
  return __builtin_elementwise_fma(a, b, c);
#else
  return (float2v){ fmaf(a[0], b[0], c[0]), fmaf(a[1], b[1], c[1]) };
#endif
}

// Load N consecutive bf16 from LDS (16B-aligned, N multiple of 8) -> f32 regs.
template<int N>
__device__ __forceinline__ void ldw(const unsigned short* p, float* dst){
  #pragma unroll
  for (int q = 0; q < N/8; ++q){
    union { short8 v; unsigned short u[8]; } t;
    t.v = *reinterpret_cast<const short8*>(p + q*8);
    #pragma unroll
    for (int i = 0; i < 8; ++i) dst[q*8 + i] = bf2f(t.u[i]);
  }
}

// Same, but into float2 pairs (dst[q] = {elem 2q, elem 2q+1}).
template<int N>
__device__ __forceinline__ void ldw2(const unsigned short* p, float2v* dst){
  #pragma unroll
  for (int q = 0; q < N/8; ++q){
    union { short8 v; unsigned short u[8]; } t;
    t.v = *reinterpret_cast<const short8*>(p + q*8);
    #pragma unroll
    for (int i = 0; i < 4; ++i)
      dst[q*4 + i] = (float2v){ bf2f(t.u[2*i]), bf2f(t.u[2*i+1]) };
  }
}

#define NZ(c) ((c) > 1e-12 || (c) < -1e-12)

constexpr int XSH = 248;  // x-tile LDS row stride (ushorts): 496B, 2-way banks

// ---------------------------------------------------------------------------
// Weight preprocessing v3: folded + fragment-tiled (identical to round 7).
// grid (136, 3), block 256.
// ---------------------------------------------------------------------------
__global__ __launch_bounds__(256)
void tsq_prep(const float* __restrict__ w0, const float* __restrict__ w1,
              const float* __restrict__ w2, const float* __restrict__ w3,
              const float* __restrict__ w4, const float* __restrict__ w5,
              const float* __restrict__ w6, const float* __restrict__ w7,
              const float* __restrict__ w8, const float* __restrict__ w9,
              const float* __restrict__ w10, unsigned short* __restrict__ wt){
  const int s   = blockIdx.x;
  const int g   = blockIdx.y;
  const int tid = threadIdx.x;

  const int lw  = 6 - g;                 // log2(Wn): 6,5,4
  const int Wn  = 1 << lw;               // 64,32,16
  const int NT  = Wn >> 4;               // 4,2,1
  int Smax;
  unsigned short* obase;
  if (g == 0){ Smax = 136; obase = wt; }
  else if (g == 1){ Smax = 80; obase = wt + WT1_OFF; }
  else { Smax = 72; obase = wt + WT2_OFF; }
  if (s >= Smax) return;

  __shared__ unsigned short tl[32*66];   // max 32 x (64+2)
  const int st = Wn + 2;

  // ---- phase 1: gather/scale/convert (with mirror folds), coalesced in n ----
  const int nel = 32 << lw;              // == NT*512
  for (int idx = tid; idx < nel; idx += 256){
    const int kk = idx >> lw, n = idx & (Wn - 1);
    float v;
    if (g == 0){
      if (s < 64){                                   // (0,0,0) u<32, all v
        const int u = s >> 1, vv = (s & 1)*32 + kk;
        v = w0[(u*64 + vv)*64 + n];
        if (s & 1) v += w0[(vv*64 + u)*64 + n];      // fold dropped (u>=32,v<32)
        v *= (float)S000;
      } else if (s < 96){                            // (0,0,0) u>=32, v>=32
        const int u = s - 32, vv = 32 + kk;
        v = w0[(u*64 + vv)*64 + n] * (float)S000;
      } else if (s < 128){                           // (1,1,0) K=u*32+v
        v = w4[((s-96)*32 + kk)*64 + n] * (float)S110;
      } else {                                       // (2,2,0) K=u*16+v
        v = w9[((s-128)*32 + kk)*64 + n] * (float)S220;
      }
    } else if (g == 1){
      const int k = s*32 + kk;
      if (s < 64){                                   // (0,1,1)+(1,0,1), K=A1*64+A0
        v = w1[((k&63)*32 + (k>>6))*32 + n] * (float)S011
          + w3[k*32 + n] * (float)S101;
      } else {                                       // (1,2,1)+(2,1,1), K=v2*32+u1
        const int kr = k - 2048;
        const int u1 = kr & 31, v2 = kr >> 5;
        v = w6[(u1*16 + v2)*32 + n] * (float)S121
          + w8[(v2*32 + u1)*32 + n] * (float)S211;
      }
    } else {
      const int k = s*32 + kk;
      if (s < 32){                                   // (0,2,2)+(2,0,2), K=v2*64+u0
        v = w2[((k&63)*16 + (k>>6))*16 + n] * (float)S022
          + w7[k*16 + n] * (float)S202;
      } else if (s < 64){                            // (1,1,2) K=u*32+v
        v = w5[(k-1024)*16 + n] * (float)S112;
      } else {                                       // (2,2,2) K=u*16+v
        v = w10[(k-2048)*16 + n] * (float)S222;
      }
    }
    tl[kk*st + n] = f2bf_rne(v);
  }
  __syncthreads();

  // ---- phase 2: contiguous fragment-order write ----
  unsigned short* o = obase + (size_t)s*NT*512;
  const int nout = NT*512;
  for (int idx = tid; idx < nout; idx += 256){
    const int nt  = idx >> 9;
    const int r   = idx & 511;
    const int col = r >> 5;
    const int kk  = r & 31;
    o[idx] = tl[kk*st + nt*16 + col];
  }
}

// ---------------------------------------------------------------------------
// Main kernel.  grid (3, 313), block 512 (8 waves).  blockIdx.x = GEMM id,
// blockIdx.y = batch tile of 64 rows.  x tile staged in LDS as bf16 (RNE).
// A-generation uses packed f32 (float2 -> v_pk_mul/fma_f32).
// ---------------------------------------------------------------------------
__global__ __launch_bounds__(512, 4)
void tsq_main(const float* __restrict__ x, const unsigned short* __restrict__ wt,
              float* __restrict__ out){
  __shared__ unsigned short lxh[64*XSH];
  const int g    = blockIdx.x;
  const int b0   = blockIdx.y * 64;
  const int tid  = threadIdx.x;
  const int wv   = tid >> 6;      // 0..7
  const int lane = tid & 63;
  const int col  = lane & 15;
  const int tg   = lane >> 4;
  const int fo   = col*32 + tg*8; // per-lane fragment offset within a 512-el tile

  // ---- stage x tile: f32 global -> RNE bf16 LDS (uint2 = 4 elems / store) ----
  for (int i = tid; i < 64*60; i += 512){
    const int r = i / 60, c = i - r*60;
    int gb = b0 + r; if (gb > 19999) gb = 19999;
    const float4 v = *(reinterpret_cast<const float4*>(x + (size_t)gb*240) + c);
    uint2 p; p.x = pkbf(v.x, v.y); p.y = pkbf(v.z, v.w);
    *reinterpret_cast<uint2*>(&lxh[r*XSH + c*4]) = p;
  }
  __syncthreads();

  const float4v z4 = {0.f, 0.f, 0.f, 0.f};

  if (g == 0){
    // ====== GEMM 0: out[:,0:64], K=4352, 2-way M (mh) x 4-way K (kh) ======
    const unsigned short* bpl = wt + fo;
    const int mh  = wv >> 2;
    const int kh  = wv & 3;
    const int par = kh & 1;       // s-parity for s<64 (constant per wave)

    float4v acc[2][4];
    #pragma unroll
    for (int mt = 0; mt < 2; ++mt)
      #pragma unroll
      for (int nt = 0; nt < 4; ++nt) acc[mt][nt] = z4;

    const unsigned short* rbase[2];
    #pragma unroll
    for (int mt = 0; mt < 2; ++mt) rbase[mt] = &lxh[(mh*32 + mt*16 + col)*XSH];

    // wA = x0 window for parity `par` (s<64); wB = x0 upper half (s>=64).
    float2v wA[2][4], wB[2][4];
    #pragma unroll
    for (int mt = 0; mt < 2; ++mt){
      ldw2<8>(rbase[mt] + par*32 + tg*8, wA[mt]);
      ldw2<8>(rbase[mt] + 32 + tg*8,     wB[mt]);
    }

    // --- (0,0,0) part A: s in [0,64), u = s>>1 (<32), window = wA ---
    for (int s = kh; s < 64; s += 4){
      short8 bf[4];
      #pragma unroll
      for (int nt = 0; nt < 4; ++nt) bf[nt] = ldB(bpl + (s*4 + nt)*512);
      const int u = s >> 1;
      #pragma unroll
      for (int mt = 0; mt < 2; ++mt){
        const float2v xu2 = b2(bf2f(rbase[mt][u]));
        float2v sv[4];
        #pragma unroll
        for (int q = 0; q < 4; ++q) sv[q] = xu2 * wA[mt][q];
        const short8 af = mkfrag2(sv);
        #pragma unroll
        for (int nt = 0; nt < 4; ++nt) acc[mt][nt] = MFMA(af, bf[nt], acc[mt][nt]);
      }
    }
    // --- (0,0,0) part B: s in [64,96), u = s-32 (>=32), window = wB ---
    for (int s = 64 + kh; s < 96; s += 4){
      short8 bf[4];
      #pragma unroll
      for (int nt = 0; nt < 4; ++nt) bf[nt] = ldB(bpl + (s*4 + nt)*512);
      const int u = s - 32;
      #pragma unroll
      for (int mt = 0; mt < 2; ++mt){
        const float2v xu2 = b2(bf2f(rbase[mt][u]));
        float2v sv[4];
        #pragma unroll
        for (int q = 0; q < 4; ++q) sv[q] = xu2 * wB[mt][q];
        const short8 af = mkfrag2(sv);
        #pragma unroll
        for (int nt = 0; nt < 4; ++nt) acc[mt][nt] = MFMA(af, bf[nt], acc[mt][nt]);
      }
    }
    // --- (1,1,0): s in [96,128), u = s-96, K=u*32+v ---
    // x1 window transposed to pair layout: x1{A,B,C}[mt][q] = component {0,1,2}
    // of rows (2q, 2q+1) of x1[tg*8 + t].
    float2v x1A[2][4], x1B[2][4], x1C[2][4];
    #pragma unroll
    for (int mt = 0; mt < 2; ++mt){
      float tmp[24];
      ldw<24>(rbase[mt] + 64 + tg*24, tmp);
      #pragma unroll
      for (int q = 0; q < 4; ++q){
        x1A[mt][q] = (float2v){ tmp[(2*q)*3+0], tmp[(2*q+1)*3+0] };
        x1B[mt][q] = (float2v){ tmp[(2*q)*3+1], tmp[(2*q+1)*3+1] };
        x1C[mt][q] = (float2v){ tmp[(2*q)*3+2], tmp[(2*q+1)*3+2] };
      }
    }
    for (int s = 96 + kh; s < 128; s += 4){
      short8 bf[4];
      #pragma unroll
      for (int nt = 0; nt < 4; ++nt) bf[nt] = ldB(bpl + (s*4 + nt)*512);
      const int u = s - 96;
      #pragma unroll
      for (int mt = 0; mt < 2; ++mt){
        const unsigned short* rb = rbase[mt];
        const float2v u0 = b2(bf2f(rb[64+u*3]));
        const float2v u1 = b2(bf2f(rb[64+u*3+1]));
        const float2v u2 = b2(bf2f(rb[64+u*3+2]));
        float2v sv[4];
        #pragma unroll
        for (int q = 0; q < 4; ++q)
          sv[q] = pfma(u0, x1A[mt][q], pfma(u1, x1B[mt][q], u2 * x1C[mt][q]));
        const short8 af = mkfrag2(sv);
        #pragma unroll
        for (int nt = 0; nt < 4; ++nt) acc[mt][nt] = MFMA(af, bf[nt], acc[mt][nt]);
      }
    }
    // --- (2,2,0): s in [128,136), K=u*16+v (2 iters: scalar, xv per mt) ---
    for (int s = 128 + kh; s < 136; s += 4){
      short8 bf[4];
      #pragma unroll
      for (int nt = 0; nt < 4; ++nt) bf[nt] = ldB(bpl + (s*4 + nt)*512);
      const int ub = (s - 128)*2 + (tg >> 1);
      #pragma unroll
      for (int mt = 0; mt < 2; ++mt){
        const unsigned short* rb = rbase[mt];
        float xu[5];
        #pragma unroll
        for (int i = 0; i < 5; ++i) xu[i] = bf2f(rb[160 + ub*5 + i]);
        float xv[40];
        ldw<40>(rb + 160 + (tg&1)*40, xv);
        float sv[8];
        #pragma unroll
        for (int t = 0; t < 8; ++t){
          float a = 0.f;
          #pragma unroll
          for (int i = 0; i < 5; ++i) a = fmaf(xu[i], xv[t*5+i], a);
          sv[t] = a;
        }
        union { short8 v; unsigned u[4]; } f;
        f.u[0] = pkbf(sv[0], sv[1]); f.u[1] = pkbf(sv[2], sv[3]);
        f.u[2] = pkbf(sv[4], sv[5]); f.u[3] = pkbf(sv[6], sv[7]);
        #pragma unroll
        for (int nt = 0; nt < 4; ++nt) acc[mt][nt] = MFMA(f.v, bf[nt], acc[mt][nt]);
      }
    }
    // --- 4-way K reduction, 3 passes of 16 KB (scratch = lxh as f32) ---
    __syncthreads();
    float* red = reinterpret_cast<float*>(lxh);
    #pragma unroll
    for (int p = 1; p <= 3; ++p){
      if (kh == p){
        #pragma unroll
        for (int mt = 0; mt < 2; ++mt)
          #pragma unroll
          for (int nt = 0; nt < 4; ++nt)
            #pragma unroll
            for (int r = 0; r < 4; ++r)
              red[mh*2048 + (mt*4 + nt)*256 + (tg*4 + r)*16 + col] = acc[mt][nt][r];
      }
      __syncthreads();
      if (kh == 0){
        #pragma unroll
        for (int mt = 0; mt < 2; ++mt)
          #pragma unroll
          for (int nt = 0; nt < 4; ++nt)
            #pragma unroll
            for (int r = 0; r < 4; ++r)
              acc[mt][nt][r] += red[mh*2048 + (mt*4 + nt)*256 + (tg*4 + r)*16 + col];
      }
      __syncthreads();
    }
    if (kh == 0){
      #pragma unroll
      for (int mt = 0; mt < 2; ++mt)
        #pragma unroll
        for (int r = 0; r < 4; ++r){
          const int b = b0 + mh*32 + mt*16 + tg*4 + r;
          if (b < 20000){
            #pragma unroll
            for (int nt = 0; nt < 4; ++nt)
              out[(size_t)b*240 + nt*16 + col] = acc[mt][nt][r];
          }
        }
    }

  } else if (g == 1){
    // ===== GEMM 1: out[:,64:160] (w*3+k), K=2560, 4-way M (mq) x 2-way K =====
    const unsigned short* bpl = wt + WT1_OFF + fo;
    const int mq = wv >> 1;
    const int kh = wv & 1;
    const unsigned short* rb = &lxh[(mq*16 + col)*XSH];

    float4v acc[3][2];
    #pragma unroll
    for (int k3 = 0; k3 < 3; ++k3)
      #pragma unroll
      for (int nt = 0; nt < 2; ++nt) acc[k3][nt] = z4;

    float2v w2[4];
    ldw2<8>(rb + kh*32 + tg*8, w2);
    float2v x1A[4], x1B[4], x1C[4];
    {
      float tmp[24];
      ldw<24>(rb + 64 + tg*24, tmp);
      #pragma unroll
      for (int q = 0; q < 4; ++q){
        x1A[q] = (float2v){ tmp[(2*q)*3+0], tmp[(2*q+1)*3+0] };
        x1B[q] = (float2v){ tmp[(2*q)*3+1], tmp[(2*q+1)*3+1] };
        x1C[q] = (float2v){ tmp[(2*q)*3+2], tmp[(2*q+1)*3+2] };
      }
    }

    // --- (0,1,1)+(1,0,1) folded: s in [0,64), K=A1*64+A0 ---
    for (int s = kh; s < 64; s += 2){
      const short8 bf0 = ldB(bpl + (s*2    )*512);
      const short8 bf1 = ldB(bpl + (s*2 + 1)*512);
      const int m = s >> 1;
      const float2v c0 = b2(bf2f(rb[64+m*3]));
      const float2v c1 = b2(bf2f(rb[64+m*3+1]));
      const float2v c2 = b2(bf2f(rb[64+m*3+2]));
      float2v sv0[4], sv1[4], sv2[4];
      #pragma unroll
      for (int q = 0; q < 4; ++q){
        sv0[q] = w2[q]*c0; sv1[q] = w2[q]*c1; sv2[q] = w2[q]*c2;
      }
      const short8 a0 = mkfrag2(sv0), a1 = mkfrag2(sv1), a2 = mkfrag2(sv2);
      acc[0][0] = MFMA(a0, bf0, acc[0][0]);
      acc[0][1] = MFMA(a0, bf1, acc[0][1]);
      acc[1][0] = MFMA(a1, bf0, acc[1][0]);
      acc[1][1] = MFMA(a1, bf1, acc[1][1]);
      acc[2][0] = MFMA(a2, bf0, acc[2][0]);
      acc[2][1] = MFMA(a2, bf1, acc[2][1]);
    }
    // --- (1,2,1)+(2,1,1) folded: s in [64,80), K=v2*32+u1, precontracted ---
    for (int s = 64 + kh; s < 80; s += 2){
      const short8 bf0 = ldB(bpl + (s*2    )*512);
      const short8 bf1 = ldB(bpl + (s*2 + 1)*512);
      const int v2 = s - 64;
      float xq[5];
      #pragma unroll
      for (int j = 0; j < 5; ++j) xq[j] = bf2f(rb[160 + v2*5 + j]);
      // t3[kk][i] = sum_j C121[i][j][kk] * xq[j]
      float t3[3][3];
      #pragma unroll
      for (int kk = 0; kk < 3; ++kk)
        #pragma unroll
        for (int i = 0; i < 3; ++i){
          float a = 0.f;
          #pragma unroll
          for (int j = 0; j < 5; ++j){
            const double cd = T121.v[i][j][kk];
            if (NZ(cd)) a = fmaf((float)cd, xq[j], a);
          }
          t3[kk][i] = a;
        }
      float2v sv0[4], sv1[4], sv2[4];
      {
        const float2v t00 = b2(t3[0][0]), t01 = b2(t3[0][1]), t02 = b2(t3[0][2]);
        const float2v t10 = b2(t3[1][0]), t11 = b2(t3[1][1]), t12 = b2(t3[1][2]);
        const float2v t20 = b2(t3[2][0]), t21 = b2(t3[2][1]), t22 = b2(t3[2][2]);
        #pragma unroll
        for (int q = 0; q < 4; ++q){
          sv0[q] = pfma(x1A[q], t00, pfma(x1B[q], t01, x1C[q]*t02));
          sv1[q] = pfma(x1A[q], t10, pfma(x1B[q], t11, x1C[q]*t12));
          sv2[q] = pfma(x1A[q], t20, pfma(x1B[q], t21, x1C[q]*t22));
        }
      }
      const short8 a0 = mkfrag2(sv0), a1 = mkfrag2(sv1), a2 = mkfrag2(sv2);
      acc[0][0] = MFMA(a0, bf0, acc[0][0]);
      acc[0][1] = MFMA(a0, bf1, acc[0][1]);
      acc[1][0] = MFMA(a1, bf0, acc[1][0]);
      acc[1][1] = MFMA(a1, bf1, acc[1][1]);
      acc[2][0] = MFMA(a2, bf0, acc[2][0]);
      acc[2][1] = MFMA(a2, bf1, acc[2][1]);
    }
    // --- 2-way K reduction + store (3 consecutive floats per (b,w)) ---
    __syncthreads();
    float* red = reinterpret_cast<float*>(lxh);
    if (kh == 1){
      #pragma unroll
      for (int k3 = 0; k3 < 3; ++k3)
        #pragma unroll
        for (int nt = 0; nt < 2; ++nt)
          #pragma unroll
          for (int r = 0; r < 4; ++r)
            red[mq*1536 + (k3*2 + nt)*256 + (tg*4 + r)*16 + col] = acc[k3][nt][r];
    }
    __syncthreads();
    if (kh == 0){
      #pragma unroll
      for (int r = 0; r < 4; ++r){
        const int b = b0 + mq*16 + tg*4 + r;
        if (b < 20000){
          #pragma unroll
          for (int nt = 0; nt < 2; ++nt){
            const int w2i = nt*16 + col;
            float* o = out + (size_t)b*240 + 64 + 3*w2i;
            #pragma unroll
            for (int k3 = 0; k3 < 3; ++k3)
              o[k3] = acc[k3][nt][r]
                    + red[mq*1536 + (k3*2 + nt)*256 + (tg*4 + r)*16 + col];
          }
        }
      }
    }

  } else {
    // ===== GEMM 2: out[:,160:240] (w*5+k), K=2304, 4-way M (mq) x 2-way K =====
    const unsigned short* bpl = wt + WT2_OFF + fo;
    const int mq = wv >> 1;
    const int kh = wv & 1;
    const unsigned short* rb = &lxh[(mq*16 + col)*XSH];

    float4v acc[5] = { z4, z4, z4, z4, z4 };

    float2v w2[4];
    ldw2<8>(rb + kh*32 + tg*8, w2);
    float2v x1A[4], x1B[4], x1C[4];
    {
      float tmp[24];
      ldw<24>(rb + 64 + tg*24, tmp);
      #pragma unroll
      for (int q = 0; q < 4; ++q){
        x1A[q] = (float2v){ tmp[(2*q)*3+0], tmp[(2*q+1)*3+0] };
        x1B[q] = (float2v){ tmp[(2*q)*3+1], tmp[(2*q+1)*3+1] };
        x1C[q] = (float2v){ tmp[(2*q)*3+2], tmp[(2*q+1)*3+2] };
      }
    }

    // --- (0,2,2)+(2,0,2) folded: s in [0,32), K=v2*64+u0 ---
    for (int s = kh; s < 32; s += 2){
      const short8 bf = ldB(bpl + s*512);
      const int v2 = s >> 1;
      float2v sv[5][4];
      #pragma unroll
      for (int k5 = 0; k5 < 5; ++k5){
        const float2v xq2 = b2(bf2f(rb[160 + v2*5 + k5]));
        #pragma unroll
        for (int q = 0; q < 4; ++q) sv[k5][q] = w2[q] * xq2;
      }
      #pragma unroll
      for (int k5 = 0; k5 < 5; ++k5) acc[k5] = MFMA(mkfrag2(sv[k5]), bf, acc[k5]);
    }
    // --- (1,1,2): s in [32,64), K=u*32+v, precontracted ---
    for (int s = 32 + kh; s < 64; s += 2){
      const short8 bf = ldB(bpl + s*512);
      const int u = s - 32;
      float xu[3];
      #pragma unroll
      for (int i = 0; i < 3; ++i) xu[i] = bf2f(rb[64 + u*3 + i]);
      // t5[kk][j] = sum_i C112[i][j][kk] * xu[i]
      float t5[5][3];
      #pragma unroll
      for (int kk = 0; kk < 5; ++kk)
        #pragma unroll
        for (int j = 0; j < 3; ++j){
          float a = 0.f;
          #pragma unroll
          for (int i = 0; i < 3; ++i){
            const double cd = T112.v[i][j][kk];
            if (NZ(cd)) a = fmaf((float)cd, xu[i], a);
          }
          t5[kk][j] = a;
        }
      float2v sv[5][4];
      #pragma unroll
      for (int kk = 0; kk < 5; ++kk){
        const float2v c0 = b2(t5[kk][0]), c1 = b2(t5[kk][1]), c2 = b2(t5[kk][2]);
        #pragma unroll
        for (int q = 0; q < 4; ++q)
          sv[kk][q] = pfma(x1A[q], c0, pfma(x1B[q], c1, x1C[q]*c2));
      }
      #pragma unroll
      for (int k5 = 0; k5 < 5; ++k5) acc[k5] = MFMA(mkfrag2(sv[k5]), bf, acc[k5]);
    }
    // --- (2,2,2): s in [64,72), K=u*16+v, precontracted per-lane ---
    {
      // x2 window transposed: tV[j][q] = component j of rows (2q, 2q+1).
      float2v tV[5][4];
      {
        float x2w[40];
        ldw<40>(rb + 160 + (tg&1)*40, x2w);
        #pragma unroll
        for (int j = 0; j < 5; ++j)
          #pragma unroll
          for (int q = 0; q < 4; ++q)
            tV[j][q] = (float2v){ x2w[(2*q)*5+j], x2w[(2*q+1)*5+j] };
      }
      for (int s = 64 + kh; s < 72; s += 2){
        const short8 bf = ldB(bpl + s*512);
        const int ub = (s - 64)*2 + (tg >> 1);
        float xu[5];
        #pragma unroll
        for (int i = 0; i < 5; ++i) xu[i] = bf2f(rb[160 + ub*5 + i]);
        // t5[kk][j] = sum_i C222[i][j][kk] * xu[i]
        float t5[5][5];
        #pragma unroll
        for (int kk = 0; kk < 5; ++kk)
          #pragma unroll
          for (int j = 0; j < 5; ++j){
            float a = 0.f;
            #pragma unroll
            for (int i = 0; i < 5; ++i){
              const double cd = T222.v[i][j][kk];
              if (NZ(cd)) a = fmaf((float)cd, xu[i], a);
            }
            t5[kk][j] = a;
          }
        float2v sv[5][4];
        #pragma unroll
        for (int kk = 0; kk < 5; ++kk){
          float2v a[4];
          const float2v c0 = b2(t5[kk][0]);
          #pragma unroll
          for (int q = 0; q < 4; ++q) a[q] = tV[0][q] * c0;
          #pragma unroll
          for (int j = 1; j < 5; ++j){
            const float2v cj = b2(t5[kk][j]);
            #pragma unroll
            for (int q = 0; q < 4; ++q) a[q] = pfma(tV[j][q], cj, a[q]);
          }
          #pragma unroll
          for (int q = 0; q < 4; ++q) sv[kk][q] = a[q];
        }
        #pragma unroll
        for (int k5 = 0; k5 < 5; ++k5) acc[k5] = MFMA(mkfrag2(sv[k5]), bf, acc[k5]);
      }
    }
    // --- 2-way K reduction + store (5 consecutive floats per (b,w)) ---
    __syncthreads();
    float* red = reinterpret_cast<float*>(lxh);
    if (kh == 1){
      #pragma unroll
      for (int k5 = 0; k5 < 5; ++k5)
        #pragma unroll
        for (int r = 0; r < 4; ++r)
          red[mq*1280 + k5*256 + (tg*4 + r)*16 + col] = acc[k5][r];
    }
    __syncthreads();
    if (kh == 0){
      #pragma unroll
      for (int r = 0; r < 4; ++r){
        const int b = b0 + mq*16 + tg*4 + r;
        if (b < 20000){
          float* o = out + (size_t)b*240 + 160 + 5*col;
          #pragma unroll
          for (int k5 = 0; k5 < 5; ++k5)
            o[k5] = acc[k5][r] + red[mq*1280 + k5*256 + (tg*4 + r)*16 + col];
        }
      }
    }
  }
}

// ---------------------------------------------------------------------------
extern "C" void kernel_launch(void* const* d_in, const int* in_sizes, int n_in,
                              void* d_out, int out_size, void* d_ws, size_t ws_size,
                              hipStream_t stream){
  (void)in_sizes; (void)n_in; (void)out_size; (void)ws_size;
  const float* x = (const float*)d_in[0];
  const float* w[11];
  for (int i = 0; i < 11; ++i) w[i] = (const float*)d_in[1 + i];
  unsigned short* wt = (unsigned short*)d_ws;
  float* out = (float*)d_out;

  dim3 gp(136, 3);
  tsq_prep<<<gp, 256, 0, stream>>>(w[0], w[1], w[2], w[3], w[4], w[5],
                                   w[6], w[7], w[8], w[9], w[10], wt);
  dim3 gm(3, 313);
  tsq_main<<<gm, 512, 0, stream>>>(x, wt, out);
}

// Round 11
// 161.560 us; speedup vs baseline: 1.5518x; 1.0132x over previous
//
#include <hip/hip_runtime.h>
#include <stdint.h>
#include <stddef.h>

// ============================================================================
// HTensorSquare: out[b] = sum_paths alpha * einsum(uvw,ijk,bui,bvj->bwk)
// Irreps in/out: 64x0e + 32x1o + 16x2e  (DIM 240), B = 20000.
// Fused into 3 GEMMs, A-operand generated in registers (packed f32), B =
// preprocessed bf16 weights in MFMA-fragment tile order.  K folded (round 7);
// bf16 x-tile in LDS (round 9); packed-f32 A-gen (round 10).
// Round-11: OPAQUE-INDEX software pipelining.  Rounds 5/6 failed because the
// compiler proved prefetch(i) == current(i+1) and un-rotated (VGPR stayed 64).
// Now the prefetch *index* passes through asm("":"+v") -- address unprovable,
// rotation preserved, loads issue a full iteration ahead (B: L2 ~250cyc;
// LDS scalars: ~120cyc) while address-space info (global_load/ds_read) is
// retained.  Also: grid swapped to (313,3) so the longest blocks (g0)
// dispatch first (LPT, shrinks straggler tail).
// ============================================================================

// ---------------------------------------------------------------------------
// Compile-time Clebsch-Gordan machinery (exact port of the reference numpy).
// ---------------------------------------------------------------------------
namespace cg {

struct Cx { double re, im; };
constexpr Cx cmul(Cx a, Cx b){ return { a.re*b.re - a.im*b.im, a.re*b.im + a.im*b.re }; }

constexpr double fact(int n){ double r = 1.0; for (int i = 2; i <= n; ++i) r *= (double)i; return r; }

constexpr double csqrt(double x){
  if (x <= 0.0) return 0.0;
  double r = x > 1.0 ? x : 1.0;
  for (int i = 0; i < 50; ++i) r = 0.5*(r + x/r);
  return r;
}

constexpr double neg1pow(int k){ return (k % 2 == 0) ? 1.0 : -1.0; }

constexpr double su2_cg(int j1,int m1,int j2,int m2,int j3,int m3){
  if (m3 != m1 + m2) return 0.0;
  int vmin = -j1 + j2 + m3;
  if (-j1 + m1 > vmin) vmin = -j1 + m1;
  if (0 > vmin) vmin = 0;
  int vmax = j2 + j3 + m1;
  if (j3 - j1 + j2 < vmax) vmax = j3 - j1 + j2;
  if (j3 + m3 < vmax) vmax = j3 + m3;
  if (vmax < vmin) return 0.0;
  double C = csqrt((2.0*j3 + 1.0)*fact(j3+j1-j2)*fact(j3-j1+j2)*fact(j1+j2-j3)
                   *fact(j3+m3)*fact(j3-m3)
                   /(fact(j1+j2+j3+1)*fact(j1-m1)*fact(j1+m1)*fact(j2-m2)*fact(j2+m2)));
  double S = 0.0;
  for (int v = vmin; v <= vmax; ++v)
    S += neg1pow(v + j2 + m2)*fact(j2+j3+m1-v)*fact(j1-m1+v)
       /(fact(v)*fact(j3-j1+j2-v)*fact(j3+m3-v)*fact(v+j1-j2-m3));
  return C*S;
}

struct QM { Cx v[5][5]; };
constexpr QM qmat(int l){
  QM q{};
  const double r2 = 0.70710678118654752440;
  for (int m = -l; m < 0; ++m){
    q.v[l+m][l-m] = Cx{ r2, 0.0 };       // q[l+m, l+|m|]
    q.v[l+m][l+m] = Cx{ 0.0, -r2 };      // q[l+m, l-|m|]
  }
  q.v[l][l] = Cx{ 1.0, 0.0 };
  for (int m = 1; m <= l; ++m){
    double s = neg1pow(m)*r2;
    q.v[l+m][l+m] = Cx{ s, 0.0 };
    q.v[l+m][l-m] = Cx{ 0.0, s };
  }
  Cx ph = (l % 4 == 0) ? Cx{1,0} : (l % 4 == 1) ? Cx{0,-1} : (l % 4 == 2) ? Cx{-1,0} : Cx{0,1};
  QM out{};
  for (int i = 0; i < 5; ++i) for (int j = 0; j < 5; ++j) out.v[i][j] = cmul(ph, q.v[i][j]);
  return out;
}

struct CGT { double v[5][5][5]; };
// Real-basis CG * sqrt(2*l3+1)   (matches reference CGS entries)
constexpr CGT cg_tab(int l1,int l2,int l3){
  double C[5][5][5] = {};
  for (int m1 = -l1; m1 <= l1; ++m1)
    for (int m2 = -l2; m2 <= l2; ++m2)
      for (int m3 = -l3; m3 <= l3; ++m3)
        C[l1+m1][l2+m2][l3+m3] = su2_cg(l1,m1,l2,m2,l3,m3);
  QM Q1 = qmat(l1), Q2 = qmat(l2), Q3 = qmat(l3);
  const int n1 = 2*l1+1, n2 = 2*l2+1, n3 = 2*l3+1;
  const double norm = csqrt(2.0*l3 + 1.0);
  CGT R{};
  for (int j = 0; j < n1; ++j)
    for (int l = 0; l < n2; ++l)
      for (int m = 0; m < n3; ++m){
        Cx s{0,0};
        for (int i = 0; i < n1; ++i)
          for (int k = 0; k < n2; ++k)
            for (int n = 0; n < n3; ++n){
              double c = C[i][k][n];
              if (c != 0.0){
                Cx q3c{ Q3.v[n][m].re, -Q3.v[n][m].im };   // conj(Q3.T)[m][n]
                Cx t = cmul(cmul(Q1.v[i][j], Q2.v[k][l]), q3c);
                s.re += t.re*c; s.im += t.im*c;
              }
            }
        R.v[j][l][m] = s.re * norm;
      }
  return R;
}

constexpr double tab_sumsq(const CGT& t, int n1, int n2, int n3){
  double s = 0;
  for (int i = 0; i < n1; ++i) for (int j = 0; j < n2; ++j) for (int k = 0; k < n3; ++k)
    s += t.v[i][j][k]*t.v[i][j][k];
  return s;
}

} // namespace cg

// Full tables for the 4 non-trivial paths
constexpr cg::CGT T121 = cg::cg_tab(1,2,1);
constexpr cg::CGT T211 = cg::cg_tab(2,1,1);
constexpr cg::CGT T112 = cg::cg_tab(1,1,2);
constexpr cg::CGT T222 = cg::cg_tab(2,2,2);
// Scalar constants for delta-structured paths
constexpr double C000 = cg::cg_tab(0,0,0).v[0][0][0];
constexpr double C011 = cg::cg_tab(0,1,1).v[0][0][0];
constexpr double C022 = cg::cg_tab(0,2,2).v[0][0][0];
constexpr double C101 = cg::cg_tab(1,0,1).v[0][0][0];
constexpr double C110 = cg::cg_tab(1,1,0).v[0][0][0];
constexpr double C220 = cg::cg_tab(2,2,0).v[0][0][0];
constexpr double C202 = cg::cg_tab(2,0,2).v[0][0][0];

// Sanity checks
static_assert(C000 > 0.99 && C000 < 1.01, "C000");
static_assert(C011 > 1.72 && C011 < 1.74, "C011");
static_assert(C101 > 1.72 && C101 < 1.74, "C101");
static_assert(C022 > 2.22 && C022 < 2.25, "C022");
static_assert(C202 > 2.22 && C202 < 2.25, "C202");
static_assert(C110*C110 > 0.332 && C110*C110 < 0.334, "C110");
static_assert(C220*C220 > 0.199 && C220*C220 < 0.201, "C220");
static_assert(cg::tab_sumsq(T121,3,5,3) > 8.9  && cg::tab_sumsq(T121,3,5,3) < 9.1,  "T121");
static_assert(cg::tab_sumsq(T211,5,3,3) > 8.9  && cg::tab_sumsq(T211,5,3,3) < 9.1,  "T211");
static_assert(cg::tab_sumsq(T112,3,3,5) > 24.9 && cg::tab_sumsq(T112,3,3,5) < 25.1, "T112");
static_assert(cg::tab_sumsq(T222,5,5,5) > 24.9 && cg::tab_sumsq(T222,5,5,5) < 25.1, "T222");

// The (2,1,1)->(1,2,1) fold requires C211[i][j][k] == C121[j][i][k].
constexpr double t121_t211_swapdiff(){
  double m = 0;
  for (int i = 0; i < 5; ++i)
    for (int j = 0; j < 3; ++j)
      for (int k = 0; k < 3; ++k){
        double d = T211.v[i][j][k] - T121.v[j][i][k];
        if (d < 0) d = -d;
        if (d > m) m = d;
      }
  return m;
}
static_assert(t121_t211_swapdiff() < 1e-9, "T211 != T121^T -- fold invalid");

// Normalization (fan-in per output irrep) folded into weights.
constexpr double A0 = 1.0/cg::csqrt(5376.0);
constexpr double A1 = 1.0/cg::csqrt(5120.0);
constexpr double A2 = 1.0/cg::csqrt(3328.0);

constexpr double S000 = A0*C000, S110 = A0*C110, S220 = A0*C220;
constexpr double S011 = A1*C011, S101 = A1*C101, S121 = A1, S211 = A1;
constexpr double S022 = A2*C022, S112 = A2,      S202 = A2*C202, S222 = A2;

// Folded K extents (bf16 elements), fragment-tiled layout:
// element (n = nt*16+col, k = s*32+kk) at base_g + (s*NT_g + nt)*512 + col*32 + kk.
constexpr int K0 = 4352, K1 = 2560, K2 = 2304;   // S0=136, S1=80, S2=72
constexpr int WT1_OFF = 64*K0;              // 278528
constexpr int WT2_OFF = WT1_OFF + 32*K1;    // 360448

// ---------------------------------------------------------------------------
// Device helpers
// ---------------------------------------------------------------------------
using short8  = __attribute__((ext_vector_type(8))) short;
using float4v = __attribute__((ext_vector_type(4))) float;
using float2v = __attribute__((ext_vector_type(2))) float;

// Opaque integer: blocks the optimizer from folding prefetch(i) into
// current(i+1) (the round-5/6 un-rotation), keeps address-space knowledge.
__device__ __forceinline__ int opq(int i){ asm("" : "+v"(i)); return i; }

// RNE pack of two f32 -> packed 2x bf16 (one v_cvt_pk_bf16_f32).
__device__ __forceinline__ unsigned pkbf(float lo, float hi){
  unsigned r;
  asm("v_cvt_pk_bf16_f32 %0, %1, %2" : "=v"(r) : "v"(lo), "v"(hi));
  return r;
}

// Fragment from 4 float2 pairs (pair q = elements 2q, 2q+1).
__device__ __forceinline__ short8 mkfrag2(const float2v* s){
  union { short8 v; unsigned u[4]; } f;
  f.u[0] = pkbf(s[0][0], s[0][1]);
  f.u[1] = pkbf(s[1][0], s[1][1]);
  f.u[2] = pkbf(s[2][0], s[2][1]);
  f.u[3] = pkbf(s[3][0], s[3][1]);
  return f.v;
}

__device__ __forceinline__ short8 ldB(const unsigned short* p){
  return *reinterpret_cast<const short8*>(p);   // global_load_dwordx4
}

__device__ __forceinline__ float4v MFMA(short8 a, short8 b, float4v c){
  return __builtin_amdgcn_mfma_f32_16x16x32_bf16(a, b, c, 0, 0, 0);
}

__device__ __forceinline__ unsigned short f2bf_rne(float f){
  unsigned u = __builtin_bit_cast(unsigned, f);
  u += 0x7fffu + ((u >> 16) & 1u);
  return (unsigned short)(u >> 16);
}

// bf16 (LDS) -> f32: one shift.
__device__ __forceinline__ float bf2f(unsigned short h){
  return __builtin_bit_cast(float, (unsigned)h << 16);
}

// Packed f32 helpers (backend selects v_pk_mul_f32 / v_pk_fma_f32 on gfx950).
__device__ __forceinline__ float2v b2(float x){ return (float2v){x, x}; }
__device__ __forceinline__ float2v pfma(float2v a, float2v b, float2v c){
#if __has_builtin(__builtin_elementwise_fma)
  return __builtin_elementwise_fma(a, b, c);
#else
  return (float2v){ fmaf(a[0], b[0], c[0]), fmaf(a[1], b[1], c[1]) };
#endif
}

// Load N consecutive bf16 from LDS (16B-aligned, N multiple of 8) -> f32 regs.
template<int N>
__device__ __forceinline__ void ldw(const unsigned short* p, float* dst){
  #pragma unroll
  for (int q = 0; q < N/8; ++q){
    union { short8 v; unsigned short u[8]; } t;
    t.v = *reinterpret_cast<const short8*>(p + q*8);
    #pragma unroll
    for (int i = 0; i < 8; ++i) dst[q*8 + i] = bf2f(t.u[i]);
  }
}

// Same, but into float2 pairs (dst[q] = {elem 2q, elem 2q+1}).
template<int N>
__device__ __forceinline__ void ldw2(const unsigned short* p, float2v* dst){
  #pragma unroll
  for (int q = 0; q < N/8; ++q){
    union { short8 v; unsigned short u[8]; } t;
    t.v = *reinterpret_cast<const short8*>(p + q*8);
    #pragma unroll
    for (int i = 0; i < 4; ++i)
      dst[q*4 + i] = (float2v){ bf2f(t.u[2*i]), bf2f(t.u[2*i+1]) };
  }
}

#define NZ(c) ((c) > 1e-12 || (c) < -1e-12)

constexpr int XSH = 248;  // x-tile LDS row stride (ushorts): 496B, 2-way banks

// ---------------------------------------------------------------------------
// Weight preprocessing v3: folded + fragment-tiled (identical to round 7).
// grid (136, 3), block 256.
// ---------------------------------------------------------------------------
__global__ __launch_bounds__(256)
void tsq_prep(const float* __restrict__ w0, const float* __restrict__ w1,
              const float* __restrict__ w2, const float* __restrict__ w3,
              const float* __restrict__ w4, const float* __restrict__ w5,
              const float* __restrict__ w6, const float* __restrict__ w7,
              const float* __restrict__ w8, const float* __restrict__ w9,
              const float* __restrict__ w10, unsigned short* __restrict__ wt){
  const int s   = blockIdx.x;
  const int g   = blockIdx.y;
  const int tid = threadIdx.x;

  const int lw  = 6 - g;                 // log2(Wn): 6,5,4
  const int Wn  = 1 << lw;               // 64,32,16
  const int NT  = Wn >> 4;               // 4,2,1
  int Smax;
  unsigned short* obase;
  if (g == 0){ Smax = 136; obase = wt; }
  else if (g == 1){ Smax = 80; obase = wt + WT1_OFF; }
  else { Smax = 72; obase = wt + WT2_OFF; }
  if (s >= Smax) return;

  __shared__ unsigned short tl[32*66];   // max 32 x (64+2)
  const int st = Wn + 2;

  // ---- phase 1: gather/scale/convert (with mirror folds), coalesced in n ----
  const int nel = 32 << lw;              // == NT*512
  for (int idx = tid; idx < nel; idx += 256){
    const int kk = idx >> lw, n = idx & (Wn - 1);
    float v;
    if (g == 0){
      if (s < 64){                                   // (0,0,0) u<32, all v
        const int u = s >> 1, vv = (s & 1)*32 + kk;
        v = w0[(u*64 + vv)*64 + n];
        if (s & 1) v += w0[(vv*64 + u)*64 + n];      // fold dropped (u>=32,v<32)
        v *= (float)S000;
      } else if (s < 96){                            // (0,0,0) u>=32, v>=32
        const int u = s - 32, vv = 32 + kk;
        v = w0[(u*64 + vv)*64 + n] * (float)S000;
      } else if (s < 128){                           // (1,1,0) K=u*32+v
        v = w4[((s-96)*32 + kk)*64 + n] * (float)S110;
      } else {                                       // (2,2,0) K=u*16+v
        v = w9[((s-128)*32 + kk)*64 + n] * (float)S220;
      }
    } else if (g == 1){
      const int k = s*32 + kk;
      if (s < 64){                                   // (0,1,1)+(1,0,1), K=A1*64+A0
        v = w1[((k&63)*32 + (k>>6))*32 + n] * (float)S011
          + w3[k*32 + n] * (float)S101;
      } else {                                       // (1,2,1)+(2,1,1), K=v2*32+u1
        const int kr = k - 2048;
        const int u1 = kr & 31, v2 = kr >> 5;
        v = w6[(u1*16 + v2)*32 + n] * (float)S121
          + w8[(v2*32 + u1)*32 + n] * (float)S211;
      }
    } else {
      const int k = s*32 + kk;
      if (s < 32){                                   // (0,2,2)+(2,0,2), K=v2*64+u0
        v = w2[((k&63)*16 + (k>>6))*16 + n] * (float)S022
          + w7[k*16 + n] * (float)S202;
      } else if (s < 64){                            // (1,1,2) K=u*32+v
        v = w5[(k-1024)*16 + n] * (float)S112;
      } else {                                       // (2,2,2) K=u*16+v
        v = w10[(k-2048)*16 + n] * (float)S222;
      }
    }
    tl[kk*st + n] = f2bf_rne(v);
  }
  __syncthreads();

  // ---- phase 2: contiguous fragment-order write ----
  unsigned short* o = obase + (size_t)s*NT*512;
  const int nout = NT*512;
  for (int idx = tid; idx < nout; idx += 256){
    const int nt  = idx >> 9;
    const int r   = idx & 511;
    const int col = r >> 5;
    const int kk  = r & 31;
    o[idx] = tl[kk*st + nt*16 + col];
  }
}

// ---------------------------------------------------------------------------
// Main kernel.  grid (313, 3), block 512 (8 waves).  blockIdx.y = GEMM id
// (g0 dispatched first: longest blocks, LPT), blockIdx.x = batch tile.
// x tile staged in LDS as bf16 (RNE).  Hot loops software-pipelined with
// opaque prefetch indices (B fragments + per-s LDS scalars 1 iter ahead).
// ---------------------------------------------------------------------------
__global__ __launch_bounds__(512, 4)
void tsq_main(const float* __restrict__ x, const unsigned short* __restrict__ wt,
              float* __restrict__ out){
  __shared__ unsigned short lxh[64*XSH];
  const int g    = blockIdx.y;
  const int b0   = blockIdx.x * 64;
  const int tid  = threadIdx.x;
  const int wv   = tid >> 6;      // 0..7
  const int lane = tid & 63;
  const int col  = lane & 15;
  const int tg   = lane >> 4;
  const int fo   = col*32 + tg*8; // per-lane fragment offset within a 512-el tile

  // ---- stage x tile: f32 global -> RNE bf16 LDS (uint2 = 4 elems / store) ----
  for (int i = tid; i < 64*60; i += 512){
    const int r = i / 60, c = i - r*60;
    int gb = b0 + r; if (gb > 19999) gb = 19999;
    const float4 v = *(reinterpret_cast<const float4*>(x + (size_t)gb*240) + c);
    uint2 p; p.x = pkbf(v.x, v.y); p.y = pkbf(v.z, v.w);
    *reinterpret_cast<uint2*>(&lxh[r*XSH + c*4]) = p;
  }
  __syncthreads();

  const float4v z4 = {0.f, 0.f, 0.f, 0.f};

  if (g == 0){
    // ====== GEMM 0: out[:,0:64], K=4352, 2-way M (mh) x 4-way K (kh) ======
    const unsigned short* bpl = wt + fo;
    const int mh  = wv >> 2;
    const int kh  = wv & 3;
    const int par = kh & 1;       // s-parity for s<64 (constant per wave)

    float4v acc[2][4];
    #pragma unroll
    for (int mt = 0; mt < 2; ++mt)
      #pragma unroll
      for (int nt = 0; nt < 4; ++nt) acc[mt][nt] = z4;

    const unsigned short* rbase[2];
    #pragma unroll
    for (int mt = 0; mt < 2; ++mt) rbase[mt] = &lxh[(mh*32 + mt*16 + col)*XSH];

    // wA = x0 window for parity `par` (s<64); wB = x0 upper half (s>=64).
    float2v wA[2][4], wB[2][4];
    #pragma unroll
    for (int mt = 0; mt < 2; ++mt){
      ldw2<8>(rbase[mt] + par*32 + tg*8, wA[mt]);
      ldw2<8>(rbase[mt] + 32 + tg*8,     wB[mt]);
    }

    // --- (0,0,0) part A: s in [0,64), u = s>>1 (<32), window = wA --- (pipelined)
    {
      short8 bfc[4]; float xuc[2];
      {
        const int sq = opq(kh);
        #pragma unroll
        for (int nt = 0; nt < 4; ++nt) bfc[nt] = ldB(bpl + (sq*4 + nt)*512);
        xuc[0] = bf2f(rbase[0][sq >> 1]); xuc[1] = bf2f(rbase[1][sq >> 1]);
      }
      for (int s = kh; s < 64; s += 4){
        const int sq = opq((s + 4 < 64) ? s + 4 : s);
        short8 bfn[4];
        #pragma unroll
        for (int nt = 0; nt < 4; ++nt) bfn[nt] = ldB(bpl + (sq*4 + nt)*512);
        float xun[2];
        xun[0] = bf2f(rbase[0][sq >> 1]); xun[1] = bf2f(rbase[1][sq >> 1]);
        #pragma unroll
        for (int mt = 0; mt < 2; ++mt){
          const float2v xu2 = b2(xuc[mt]);
          float2v sv[4];
          #pragma unroll
          for (int q = 0; q < 4; ++q) sv[q] = xu2 * wA[mt][q];
          const short8 af = mkfrag2(sv);
          #pragma unroll
          for (int nt = 0; nt < 4; ++nt) acc[mt][nt] = MFMA(af, bfc[nt], acc[mt][nt]);
        }
        #pragma unroll
        for (int nt = 0; nt < 4; ++nt) bfc[nt] = bfn[nt];
        xuc[0] = xun[0]; xuc[1] = xun[1];
      }
    }
    // --- (0,0,0) part B: s in [64,96), u = s-32 (>=32), window = wB --- (pipelined)
    {
      short8 bfc[4]; float xuc[2];
      {
        const int sq = opq(64 + kh);
        #pragma unroll
        for (int nt = 0; nt < 4; ++nt) bfc[nt] = ldB(bpl + (sq*4 + nt)*512);
        xuc[0] = bf2f(rbase[0][sq - 32]); xuc[1] = bf2f(rbase[1][sq - 32]);
      }
      for (int s = 64 + kh; s < 96; s += 4){
        const int sq = opq((s + 4 < 96) ? s + 4 : s);
        short8 bfn[4];
        #pragma unroll
        for (int nt = 0; nt < 4; ++nt) bfn[nt] = ldB(bpl + (sq*4 + nt)*512);
        float xun[2];
        xun[0] = bf2f(rbase[0][sq - 32]); xun[1] = bf2f(rbase[1][sq - 32]);
        #pragma unroll
        for (int mt = 0; mt < 2; ++mt){
          const float2v xu2 = b2(xuc[mt]);
          float2v sv[4];
          #pragma unroll
          for (int q = 0; q < 4; ++q) sv[q] = xu2 * wB[mt][q];
          const short8 af = mkfrag2(sv);
          #pragma unroll
          for (int nt = 0; nt < 4; ++nt) acc[mt][nt] = MFMA(af, bfc[nt], acc[mt][nt]);
        }
        #pragma unroll
        for (int nt = 0; nt < 4; ++nt) bfc[nt] = bfn[nt];
        xuc[0] = xun[0]; xuc[1] = xun[1];
      }
    }
    // --- (1,1,0): s in [96,128), u = s-96, K=u*32+v --- (pipelined)
    float2v x1A[2][4], x1B[2][4], x1C[2][4];
    #pragma unroll
    for (int mt = 0; mt < 2; ++mt){
      float tmp[24];
      ldw<24>(rbase[mt] + 64 + tg*24, tmp);
      #pragma unroll
      for (int q = 0; q < 4; ++q){
        x1A[mt][q] = (float2v){ tmp[(2*q)*3+0], tmp[(2*q+1)*3+0] };
        x1B[mt][q] = (float2v){ tmp[(2*q)*3+1], tmp[(2*q+1)*3+1] };
        x1C[mt][q] = (float2v){ tmp[(2*q)*3+2], tmp[(2*q+1)*3+2] };
      }
    }
    {
      short8 bfc[4]; float uc[2][3];
      {
        const int sq = opq(96 + kh);
        #pragma unroll
        for (int nt = 0; nt < 4; ++nt) bfc[nt] = ldB(bpl + (sq*4 + nt)*512);
        const int u = sq - 96;
        #pragma unroll
        for (int mt = 0; mt < 2; ++mt){
          uc[mt][0] = bf2f(rbase[mt][64+u*3]);
          uc[mt][1] = bf2f(rbase[mt][64+u*3+1]);
          uc[mt][2] = bf2f(rbase[mt][64+u*3+2]);
        }
      }
      for (int s = 96 + kh; s < 128; s += 4){
        const int sq = opq((s + 4 < 128) ? s + 4 : s);
        short8 bfn[4];
        #pragma unroll
        for (int nt = 0; nt < 4; ++nt) bfn[nt] = ldB(bpl + (sq*4 + nt)*512);
        const int un = sq - 96;
        float unx[2][3];
        #pragma unroll
        for (int mt = 0; mt < 2; ++mt){
          unx[mt][0] = bf2f(rbase[mt][64+un*3]);
          unx[mt][1] = bf2f(rbase[mt][64+un*3+1]);
          unx[mt][2] = bf2f(rbase[mt][64+un*3+2]);
        }
        #pragma unroll
        for (int mt = 0; mt < 2; ++mt){
          const float2v u0 = b2(uc[mt][0]), u1 = b2(uc[mt][1]), u2 = b2(uc[mt][2]);
          float2v sv[4];
          #pragma unroll
          for (int q = 0; q < 4; ++q)
            sv[q] = pfma(u0, x1A[mt][q], pfma(u1, x1B[mt][q], u2 * x1C[mt][q]));
          const short8 af = mkfrag2(sv);
          #pragma unroll
          for (int nt = 0; nt < 4; ++nt) acc[mt][nt] = MFMA(af, bfc[nt], acc[mt][nt]);
        }
        #pragma unroll
        for (int nt = 0; nt < 4; ++nt) bfc[nt] = bfn[nt];
        #pragma unroll
        for (int mt = 0; mt < 2; ++mt){
          uc[mt][0] = unx[mt][0]; uc[mt][1] = unx[mt][1]; uc[mt][2] = unx[mt][2];
        }
      }
    }
    // --- (2,2,0): s in [128,136), K=u*16+v (2 iters: scalar, unpipelined) ---
    for (int s = 128 + kh; s < 136; s += 4){
      short8 bf[4];
      #pragma unroll
      for (int nt = 0; nt < 4; ++nt) bf[nt] = ldB(bpl + (s*4 + nt)*512);
      const int ub = (s - 128)*2 + (tg >> 1);
      #pragma unroll
      for (int mt = 0; mt < 2; ++mt){
        const unsigned short* rb = rbase[mt];
        float xu[5];
        #pragma unroll
        for (int i = 0; i < 5; ++i) xu[i] = bf2f(rb[160 + ub*5 + i]);
        float xv[40];
        ldw<40>(rb + 160 + (tg&1)*40, xv);
        float sv[8];
        #pragma unroll
        for (int t = 0; t < 8; ++t){
          float a = 0.f;
          #pragma unroll
          for (int i = 0; i < 5; ++i) a = fmaf(xu[i], xv[t*5+i], a);
          sv[t] = a;
        }
        union { short8 v; unsigned u[4]; } f;
        f.u[0] = pkbf(sv[0], sv[1]); f.u[1] = pkbf(sv[2], sv[3]);
        f.u[2] = pkbf(sv[4], sv[5]); f.u[3] = pkbf(sv[6], sv[7]);
        #pragma unroll
        for (int nt = 0; nt < 4; ++nt) acc[mt][nt] = MFMA(f.v, bf[nt], acc[mt][nt]);
      }
    }
    // --- 4-way K reduction, 3 passes of 16 KB (scratch = lxh as f32) ---
    __syncthreads();
    float* red = reinterpret_cast<float*>(lxh);
    #pragma unroll
    for (int p = 1; p <= 3; ++p){
      if (kh == p){
        #pragma unroll
        for (int mt = 0; mt < 2; ++mt)
          #pragma unroll
          for (int nt = 0; nt < 4; ++nt)
            #pragma unroll
            for (int r = 0; r < 4; ++r)
              red[mh*2048 + (mt*4 + nt)*256 + (tg*4 + r)*16 + col] = acc[mt][nt][r];
      }
      __syncthreads();
      if (kh == 0){
        #pragma unroll
        for (int mt = 0; mt < 2; ++mt)
          #pragma unroll
          for (int nt = 0; nt < 4; ++nt)
            #pragma unroll
            for (int r = 0; r < 4; ++r)
              acc[mt][nt][r] += red[mh*2048 + (mt*4 + nt)*256 + (tg*4 + r)*16 + col];
      }
      __syncthreads();
    }
    if (kh == 0){
      #pragma unroll
      for (int mt = 0; mt < 2; ++mt)
        #pragma unroll
        for (int r = 0; r < 4; ++r){
          const int b = b0 + mh*32 + mt*16 + tg*4 + r;
          if (b < 20000){
            #pragma unroll
            for (int nt = 0; nt < 4; ++nt)
              out[(size_t)b*240 + nt*16 + col] = acc[mt][nt][r];
          }
        }
    }

  } else if (g == 1){
    // ===== GEMM 1: out[:,64:160] (w*3+k), K=2560, 4-way M (mq) x 2-way K =====
    const unsigned short* bpl = wt + WT1_OFF + fo;
    const int mq = wv >> 1;
    const int kh = wv & 1;
    const unsigned short* rb = &lxh[(mq*16 + col)*XSH];

    float4v acc[3][2];
    #pragma unroll
    for (int k3 = 0; k3 < 3; ++k3)
      #pragma unroll
      for (int nt = 0; nt < 2; ++nt) acc[k3][nt] = z4;

    float2v w2[4];
    ldw2<8>(rb + kh*32 + tg*8, w2);
    float2v x1A[4], x1B[4], x1C[4];
    {
      float tmp[24];
      ldw<24>(rb + 64 + tg*24, tmp);
      #pragma unroll
      for (int q = 0; q < 4; ++q){
        x1A[q] = (float2v){ tmp[(2*q)*3+0], tmp[(2*q+1)*3+0] };
        x1B[q] = (float2v){ tmp[(2*q)*3+1], tmp[(2*q+1)*3+1] };
        x1C[q] = (float2v){ tmp[(2*q)*3+2], tmp[(2*q+1)*3+2] };
      }
    }

    // --- (0,1,1)+(1,0,1) folded: s in [0,64), K=A1*64+A0 --- (pipelined)
    {
      short8 b0c, b1c; float cc0, cc1, cc2;
      {
        const int sq = opq(kh);
        b0c = ldB(bpl + (sq*2)*512); b1c = ldB(bpl + (sq*2 + 1)*512);
        const int m = sq >> 1;
        cc0 = bf2f(rb[64+m*3]); cc1 = bf2f(rb[64+m*3+1]); cc2 = bf2f(rb[64+m*3+2]);
      }
      for (int s = kh; s < 64; s += 2){
        const int sq = opq((s + 2 < 64) ? s + 2 : s);
        const short8 b0n = ldB(bpl + (sq*2)*512);
        const short8 b1n = ldB(bpl + (sq*2 + 1)*512);
        const int mn = sq >> 1;
        const float cn0 = bf2f(rb[64+mn*3]), cn1 = bf2f(rb[64+mn*3+1]), cn2 = bf2f(rb[64+mn*3+2]);
        const float2v c0 = b2(cc0), c1 = b2(cc1), c2 = b2(cc2);
        float2v sv0[4], sv1[4], sv2[4];
        #pragma unroll
        for (int q = 0; q < 4; ++q){
          sv0[q] = w2[q]*c0; sv1[q] = w2[q]*c1; sv2[q] = w2[q]*c2;
        }
        const short8 a0 = mkfrag2(sv0), a1 = mkfrag2(sv1), a2 = mkfrag2(sv2);
        acc[0][0] = MFMA(a0, b0c, acc[0][0]);
        acc[0][1] = MFMA(a0, b1c, acc[0][1]);
        acc[1][0] = MFMA(a1, b0c, acc[1][0]);
        acc[1][1] = MFMA(a1, b1c, acc[1][1]);
        acc[2][0] = MFMA(a2, b0c, acc[2][0]);
        acc[2][1] = MFMA(a2, b1c, acc[2][1]);
        b0c = b0n; b1c = b1n; cc0 = cn0; cc1 = cn1; cc2 = cn2;
      }
    }
    // --- (1,2,1)+(2,1,1) folded: s in [64,80), K=v2*32+u1, precontracted --- (pipelined)
    {
      short8 b0c, b1c; float xqc[5];
      {
        const int sq = opq(64 + kh);
        b0c = ldB(bpl + (sq*2)*512); b1c = ldB(bpl + (sq*2 + 1)*512);
        const int v2 = sq - 64;
        #pragma unroll
        for (int j = 0; j < 5; ++j) xqc[j] = bf2f(rb[160 + v2*5 + j]);
      }
      for (int s = 64 + kh; s < 80; s += 2){
        const int sq = opq((s + 2 < 80) ? s + 2 : s);
        const short8 b0n = ldB(bpl + (sq*2)*512);
        const short8 b1n = ldB(bpl + (sq*2 + 1)*512);
        const int vn = sq - 64;
        float xqn[5];
        #pragma unroll
        for (int j = 0; j < 5; ++j) xqn[j] = bf2f(rb[160 + vn*5 + j]);
        // t3[kk][i] = sum_j C121[i][j][kk] * xqc[j]
        float t3[3][3];
        #pragma unroll
        for (int kk = 0; kk < 3; ++kk)
          #pragma unroll
          for (int i = 0; i < 3; ++i){
            float a = 0.f;
            #pragma unroll
            for (int j = 0; j < 5; ++j){
              const double cd = T121.v[i][j][kk];
              if (NZ(cd)) a = fmaf((float)cd, xqc[j], a);
            }
            t3[kk][i] = a;
          }
        float2v sv0[4], sv1[4], sv2[4];
        {
          const float2v t00 = b2(t3[0][0]), t01 = b2(t3[0][1]), t02 = b2(t3[0][2]);
          const float2v t10 = b2(t3[1][0]), t11 = b2(t3[1][1]), t12 = b2(t3[1][2]);
          const float2v t20 = b2(t3[2][0]), t21 = b2(t3[2][1]), t22 = b2(t3[2][2]);
          #pragma unroll
          for (int q = 0; q < 4; ++q){
            sv0[q] = pfma(x1A[q], t00, pfma(x1B[q], t01, x1C[q]*t02));
            sv1[q] = pfma(x1A[q], t10, pfma(x1B[q], t11, x1C[q]*t12));
            sv2[q] = pfma(x1A[q], t20, pfma(x1B[q], t21, x1C[q]*t22));
          }
        }
        const short8 a0 = mkfrag2(sv0), a1 = mkfrag2(sv1), a2 = mkfrag2(sv2);
        acc[0][0] = MFMA(a0, b0c, acc[0][0]);
        acc[0][1] = MFMA(a0, b1c, acc[0][1]);
        acc[1][0] = MFMA(a1, b0c, acc[1][0]);
        acc[1][1] = MFMA(a1, b1c, acc[1][1]);
        acc[2][0] = MFMA(a2, b0c, acc[2][0]);
        acc[2][1] = MFMA(a2, b1c, acc[2][1]);
        b0c = b0n; b1c = b1n;
        #pragma unroll
        for (int j = 0; j < 5; ++j) xqc[j] = xqn[j];
      }
    }
    // --- 2-way K reduction + store (3 consecutive floats per (b,w)) ---
    __syncthreads();
    float* red = reinterpret_cast<float*>(lxh);
    if (kh == 1){
      #pragma unroll
      for (int k3 = 0; k3 < 3; ++k3)
        #pragma unroll
        for (int nt = 0; nt < 2; ++nt)
          #pragma unroll
          for (int r = 0; r < 4; ++r)
            red[mq*1536 + (k3*2 + nt)*256 + (tg*4 + r)*16 + col] = acc[k3][nt][r];
    }
    __syncthreads();
    if (kh == 0){
      #pragma unroll
      for (int r = 0; r < 4; ++r){
        const int b = b0 + mq*16 + tg*4 + r;
        if (b < 20000){
          #pragma unroll
          for (int nt = 0; nt < 2; ++nt){
            const int w2i = nt*16 + col;
            float* o = out + (size_t)b*240 + 64 + 3*w2i;
            #pragma unroll
            for (int k3 = 0; k3 < 3; ++k3)
              o[k3] = acc[k3][nt][r]
                    + red[mq*1536 + (k3*2 + nt)*256 + (tg*4 + r)*16 + col];
          }
        }
      }
    }

  } else {
    // ===== GEMM 2: out[:,160:240] (w*5+k), K=2304, 4-way M (mq) x 2-way K =====
    const unsigned short* bpl = wt + WT2_OFF + fo;
    const int mq = wv >> 1;
    const int kh = wv & 1;
    const unsigned short* rb = &lxh[(mq*16 + col)*XSH];

    float4v acc[5] = { z4, z4, z4, z4, z4 };

    float2v w2[4];
    ldw2<8>(rb + kh*32 + tg*8, w2);
    float2v x1A[4], x1B[4], x1C[4];
    {
      float tmp[24];
      ldw<24>(rb + 64 + tg*24, tmp);
      #pragma unroll
      for (int q = 0; q < 4; ++q){
        x1A[q] = (float2v){ tmp[(2*q)*3+0], tmp[(2*q+1)*3+0] };
        x1B[q] = (float2v){ tmp[(2*q)*3+1], tmp[(2*q+1)*3+1] };
        x1C[q] = (float2v){ tmp[(2*q)*3+2], tmp[(2*q+1)*3+2] };
      }
    }

    // --- (0,2,2)+(2,0,2) folded: s in [0,32), K=v2*64+u0 --- (pipelined)
    {
      short8 bfc; float xqc[5];
      {
        const int sq = opq(kh);
        bfc = ldB(bpl + sq*512);
        const int v2 = sq >> 1;
        #pragma unroll
        for (int j = 0; j < 5; ++j) xqc[j] = bf2f(rb[160 + v2*5 + j]);
      }
      for (int s = kh; s < 32; s += 2){
        const int sq = opq((s + 2 < 32) ? s + 2 : s);
        const short8 bfn = ldB(bpl + sq*512);
        const int vn = sq >> 1;
        float xqn[5];
        #pragma unroll
        for (int j = 0; j < 5; ++j) xqn[j] = bf2f(rb[160 + vn*5 + j]);
        float2v sv[5][4];
        #pragma unroll
        for (int k5 = 0; k5 < 5; ++k5){
          const float2v xq2 = b2(xqc[k5]);
          #pragma unroll
          for (int q = 0; q < 4; ++q) sv[k5][q] = w2[q] * xq2;
        }
        #pragma unroll
        for (int k5 = 0; k5 < 5; ++k5) acc[k5] = MFMA(mkfrag2(sv[k5]), bfc, acc[k5]);
        bfc = bfn;
        #pragma unroll
        for (int j = 0; j < 5; ++j) xqc[j] = xqn[j];
      }
    }
    // --- (1,1,2): s in [32,64), K=u*32+v, precontracted --- (pipelined)
    {
      short8 bfc; float xuc[3];
      {
        const int sq = opq(32 + kh);
        bfc = ldB(bpl + sq*512);
        const int u = sq - 32;
        #pragma unroll
        for (int i = 0; i < 3; ++i) xuc[i] = bf2f(rb[64 + u*3 + i]);
      }
      for (int s = 32 + kh; s < 64; s += 2){
        const int sq = opq((s + 2 < 64) ? s + 2 : s);
        const short8 bfn = ldB(bpl + sq*512);
        const int un = sq - 32;
        float xun[3];
        #pragma unroll
        for (int i = 0; i < 3; ++i) xun[i] = bf2f(rb[64 + un*3 + i]);
        // t5[kk][j] = sum_i C112[i][j][kk] * xuc[i]
        float t5[5][3];
        #pragma unroll
        for (int kk = 0; kk < 5; ++kk)
          #pragma unroll
          for (int j = 0; j < 3; ++j){
            float a = 0.f;
            #pragma unroll
            for (int i = 0; i < 3; ++i){
              const double cd = T112.v[i][j][kk];
              if (NZ(cd)) a = fmaf((float)cd, xuc[i], a);
            }
            t5[kk][j] = a;
          }
        float2v sv[5][4];
        #pragma unroll
        for (int kk = 0; kk < 5; ++kk){
          const float2v c0 = b2(t5[kk][0]), c1 = b2(t5[kk][1]), c2 = b2(t5[kk][2]);
          #pragma unroll
          for (int q = 0; q < 4; ++q)
            sv[kk][q] = pfma(x1A[q], c0, pfma(x1B[q], c1, x1C[q]*c2));
        }
        #pragma unroll
        for (int k5 = 0; k5 < 5; ++k5) acc[k5] = MFMA(mkfrag2(sv[k5]), bfc, acc[k5]);
        bfc = bfn;
        xuc[0] = xun[0]; xuc[1] = xun[1]; xuc[2] = xun[2];
      }
    }
    // --- (2,2,2): s in [64,72), K=u*16+v, precontracted per-lane ---
    {
      // x2 window transposed: tV[j][q] = component j of rows (2q, 2q+1).
      float2v tV[5][4];
      {
        float x2w[40];
        ldw<40>(rb + 160 + (tg&1)*40, x2w);
        #pragma unroll
        for (int j = 0; j < 5; ++j)
          #pragma unroll
          for (int q = 0; q < 4; ++q)
            tV[j][q] = (float2v){ x2w[(2*q)*5+j], x2w[(2*q+1)*5+j] };
      }
      for (int s = 64 + kh; s < 72; s += 2){
        const short8 bf = ldB(bpl + s*512);
        const int ub = (s - 64)*2 + (tg >> 1);
        float xu[5];
        #pragma unroll
        for (int i = 0; i < 5; ++i) xu[i] = bf2f(rb[160 + ub*5 + i]);
        // t5[kk][j] = sum_i C222[i][j][kk] * xu[i]
        float t5[5][5];
        #pragma unroll
        for (int kk = 0; kk < 5; ++kk)
          #pragma unroll
          for (int j = 0; j < 5; ++j){
            float a = 0.f;
            #pragma unroll
            for (int i = 0; i < 5; ++i){
              const double cd = T222.v[i][j][kk];
              if (NZ(cd)) a = fmaf((float)cd, xu[i], a);
            }
            t5[kk][j] = a;
          }
        float2v sv[5][4];
        #pragma unroll
        for (int kk = 0; kk < 5; ++kk){
          float2v a[4];
          const float2v c0 = b2(t5[kk][0]);
          #pragma unroll
          for (int q = 0; q < 4; ++q) a[q] = tV[0][q] * c0;
          #pragma unroll
          for (int j = 1; j < 5; ++j){
            const float2v cj = b2(t5[kk][j]);
            #pragma unroll
            for (int q = 0; q < 4; ++q) a[q] = pfma(tV[j][q], cj, a[q]);
          }
          #pragma unroll
          for (int q = 0; q < 4; ++q) sv[kk][q] = a[q];
        }
        #pragma unroll
        for (int k5 = 0; k5 < 5; ++k5) acc[k5] = MFMA(mkfrag2(sv[k5]), bf, acc[k5]);
      }
    }
    // --- 2-way K reduction + store (5 consecutive floats per (b,w)) ---
    __syncthreads();
    float* red = reinterpret_cast<float*>(lxh);
    if (kh == 1){
      #pragma unroll
      for (int k5 = 0; k5 < 5; ++k5)
        #pragma unroll
        for (int r = 0; r < 4; ++r)
          red[mq*1280 + k5*256 + (tg*4 + r)*16 + col] = acc[k5][r];
    }
    __syncthreads();
    if (kh == 0){
      #pragma unroll
      for (int r = 0; r < 4; ++r){
        const int b = b0 + mq*16 + tg*4 + r;
        if (b < 20000){
          float* o = out + (size_t)b*240 + 160 + 5*col;
          #pragma unroll
          for (int k5 = 0; k5 < 5; ++k5)
            o[k5] = acc[k5][r] + red[mq*1280 + k5*256 + (tg*4 + r)*16 + col];
        }
      }
    }
  }
}

// ---------------------------------------------------------------------------
extern "C" void kernel_launch(void* const* d_in, const int* in_sizes, int n_in,
                              void* d_out, int out_size, void* d_ws, size_t ws_size,
                              hipStream_t stream){
  (void)in_sizes; (void)n_in; (void)out_size; (void)ws_size;
  const float* x = (const float*)d_in[0];
  const float* w[11];
  for (int i = 0; i < 11; ++i) w[i] = (const float*)d_in[1 + i];
  unsigned short* wt = (unsigned short*)d_ws;
  float* out = (float*)d_out;

  dim3 gp(136, 3);
  tsq_prep<<<gp, 256, 0, stream>>>(w[0], w[1], w[2], w[3], w[4], w[5],
                                   w[6], w[7], w[8], w[9], w[10], wt);
  dim3 gm(313, 3);   // x = tile (fastest), y = g: all g0 (longest) first = LPT
  tsq_main<<<gm, 512, 0, stream>>>(x, wt, out);
}

// Round 12
// 160.024 us; speedup vs baseline: 1.5667x; 1.0096x over previous
//
#include <hip/hip_runtime.h>
#include <stdint.h>
#include <stddef.h>

// ============================================================================
// HTensorSquare: out[b] = sum_paths alpha * einsum(uvw,ijk,bui,bvj->bwk)
// Irreps in/out: 64x0e + 32x1o + 16x2e  (DIM 240), B = 20000.
// Fused into 3 GEMMs, A-operand generated in registers (packed f32), B =
// preprocessed bf16 weights in MFMA-fragment tile order.  K folded (r7);
// bf16 x-tile in LDS (r9); packed-f32 A-gen (r10); LPT grid (r11).
// Round-12: CHUNKED BATCH LOADS (chunk = 2 s-values per loop body).  All
// rotation-based pipelining attempts (r5/r6/r11) were defeated by the
// scheduler sinking prefetch loads below their uses.  Chunking has no
// rotation and no recurrence: 8 B-loads (2 sub-iterations) issue into
// DISTINCT arrays at the body top, then two compute blocks follow -- one
// vmcnt-wait sequence per 2 iterations, 2x in-flight loads per wave.
// ============================================================================

// ---------------------------------------------------------------------------
// Compile-time Clebsch-Gordan machinery (exact port of the reference numpy).
// ---------------------------------------------------------------------------
namespace cg {

struct Cx { double re, im; };
constexpr Cx cmul(Cx a, Cx b){ return { a.re*b.re - a.im*b.im, a.re*b.im + a.im*b.re }; }

constexpr double fact(int n){ double r = 1.0; for (int i = 2; i <= n; ++i) r *= (double)i; return r; }

constexpr double csqrt(double x){
  if (x <= 0.0) return 0.0;
  double r = x > 1.0 ? x : 1.0;
  for (int i = 0; i < 50; ++i) r = 0.5*(r + x/r);
  return r;
}

constexpr double neg1pow(int k){ return (k % 2 == 0) ? 1.0 : -1.0; }

constexpr double su2_cg(int j1,int m1,int j2,int m2,int j3,int m3){
  if (m3 != m1 + m2) return 0.0;
  int vmin = -j1 + j2 + m3;
  if (-j1 + m1 > vmin) vmin = -j1 + m1;
  if (0 > vmin) vmin = 0;
  int vmax = j2 + j3 + m1;
  if (j3 - j1 + j2 < vmax) vmax = j3 - j1 + j2;
  if (j3 + m3 < vmax) vmax = j3 + m3;
  if (vmax < vmin) return 0.0;
  double C = csqrt((2.0*j3 + 1.0)*fact(j3+j1-j2)*fact(j3-j1+j2)*fact(j1+j2-j3)
                   *fact(j3+m3)*fact(j3-m3)
                   /(fact(j1+j2+j3+1)*fact(j1-m1)*fact(j1+m1)*fact(j2-m2)*fact(j2+m2)));
  double S = 0.0;
  for (int v = vmin; v <= vmax; ++v)
    S += neg1pow(v + j2 + m2)*fact(j2+j3+m1-v)*fact(j1-m1+v)
       /(fact(v)*fact(j3-j1+j2-v)*fact(j3+m3-v)*fact(v+j1-j2-m3));
  return C*S;
}

struct QM { Cx v[5][5]; };
constexpr QM qmat(int l){
  QM q{};
  const double r2 = 0.70710678118654752440;
  for (int m = -l; m < 0; ++m){
    q.v[l+m][l-m] = Cx{ r2, 0.0 };       // q[l+m, l+|m|]
    q.v[l+m][l+m] = Cx{ 0.0, -r2 };      // q[l+m, l-|m|]
  }
  q.v[l][l] = Cx{ 1.0, 0.0 };
  for (int m = 1; m <= l; ++m){
    double s = neg1pow(m)*r2;
    q.v[l+m][l+m] = Cx{ s, 0.0 };
    q.v[l+m][l-m] = Cx{ 0.0, s };
  }
  Cx ph = (l % 4 == 0) ? Cx{1,0} : (l % 4 == 1) ? Cx{0,-1} : (l % 4 == 2) ? Cx{-1,0} : Cx{0,1};
  QM out{};
  for (int i = 0; i < 5; ++i) for (int j = 0; j < 5; ++j) out.v[i][j] = cmul(ph, q.v[i][j]);
  return out;
}

struct CGT { double v[5][5][5]; };
// Real-basis CG * sqrt(2*l3+1)   (matches reference CGS entries)
constexpr CGT cg_tab(int l1,int l2,int l3){
  double C[5][5][5] = {};
  for (int m1 = -l1; m1 <= l1; ++m1)
    for (int m2 = -l2; m2 <= l2; ++m2)
      for (int m3 = -l3; m3 <= l3; ++m3)
        C[l1+m1][l2+m2][l3+m3] = su2_cg(l1,m1,l2,m2,l3,m3);
  QM Q1 = qmat(l1), Q2 = qmat(l2), Q3 = qmat(l3);
  const int n1 = 2*l1+1, n2 = 2*l2+1, n3 = 2*l3+1;
  const double norm = csqrt(2.0*l3 + 1.0);
  CGT R{};
  for (int j = 0; j < n1; ++j)
    for (int l = 0; l < n2; ++l)
      for (int m = 0; m < n3; ++m){
        Cx s{0,0};
        for (int i = 0; i < n1; ++i)
          for (int k = 0; k < n2; ++k)
            for (int n = 0; n < n3; ++n){
              double c = C[i][k][n];
              if (c != 0.0){
                Cx q3c{ Q3.v[n][m].re, -Q3.v[n][m].im };   // conj(Q3.T)[m][n]
                Cx t = cmul(cmul(Q1.v[i][j], Q2.v[k][l]), q3c);
                s.re += t.re*c; s.im += t.im*c;
              }
            }
        R.v[j][l][m] = s.re * norm;
      }
  return R;
}

constexpr double tab_sumsq(const CGT& t, int n1, int n2, int n3){
  double s = 0;
  for (int i = 0; i < n1; ++i) for (int j = 0; j < n2; ++j) for (int k = 0; k < n3; ++k)
    s += t.v[i][j][k]*t.v[i][j][k];
  return s;
}

} // namespace cg

// Full tables for the 4 non-trivial paths
constexpr cg::CGT T121 = cg::cg_tab(1,2,1);
constexpr cg::CGT T211 = cg::cg_tab(2,1,1);
constexpr cg::CGT T112 = cg::cg_tab(1,1,2);
constexpr cg::CGT T222 = cg::cg_tab(2,2,2);
// Scalar constants for delta-structured paths
constexpr double C000 = cg::cg_tab(0,0,0).v[0][0][0];
constexpr double C011 = cg::cg_tab(0,1,1).v[0][0][0];
constexpr double C022 = cg::cg_tab(0,2,2).v[0][0][0];
constexpr double C101 = cg::cg_tab(1,0,1).v[0][0][0];
constexpr double C110 = cg::cg_tab(1,1,0).v[0][0][0];
constexpr double C220 = cg::cg_tab(2,2,0).v[0][0][0];
constexpr double C202 = cg::cg_tab(2,0,2).v[0][0][0];

// Sanity checks
static_assert(C000 > 0.99 && C000 < 1.01, "C000");
static_assert(C011 > 1.72 && C011 < 1.74, "C011");
static_assert(C101 > 1.72 && C101 < 1.74, "C101");
static_assert(C022 > 2.22 && C022 < 2.25, "C022");
static_assert(C202 > 2.22 && C202 < 2.25, "C202");
static_assert(C110*C110 > 0.332 && C110*C110 < 0.334, "C110");
static_assert(C220*C220 > 0.199 && C220*C220 < 0.201, "C220");
static_assert(cg::tab_sumsq(T121,3,5,3) > 8.9  && cg::tab_sumsq(T121,3,5,3) < 9.1,  "T121");
static_assert(cg::tab_sumsq(T211,5,3,3) > 8.9  && cg::tab_sumsq(T211,5,3,3) < 9.1,  "T211");
static_assert(cg::tab_sumsq(T112,3,3,5) > 24.9 && cg::tab_sumsq(T112,3,3,5) < 25.1, "T112");
static_assert(cg::tab_sumsq(T222,5,5,5) > 24.9 && cg::tab_sumsq(T222,5,5,5) < 25.1, "T222");

// The (2,1,1)->(1,2,1) fold requires C211[i][j][k] == C121[j][i][k].
constexpr double t121_t211_swapdiff(){
  double m = 0;
  for (int i = 0; i < 5; ++i)
    for (int j = 0; j < 3; ++j)
      for (int k = 0; k < 3; ++k){
        double d = T211.v[i][j][k] - T121.v[j][i][k];
        if (d < 0) d = -d;
        if (d > m) m = d;
      }
  return m;
}
static_assert(t121_t211_swapdiff() < 1e-9, "T211 != T121^T -- fold invalid");

// Normalization (fan-in per output irrep) folded into weights.
constexpr double A0 = 1.0/cg::csqrt(5376.0);
constexpr double A1 = 1.0/cg::csqrt(5120.0);
constexpr double A2 = 1.0/cg::csqrt(3328.0);

constexpr double S000 = A0*C000, S110 = A0*C110, S220 = A0*C220;
constexpr double S011 = A1*C011, S101 = A1*C101, S121 = A1, S211 = A1;
constexpr double S022 = A2*C022, S112 = A2,      S202 = A2*C202, S222 = A2;

// Folded K extents (bf16 elements), fragment-tiled layout:
// element (n = nt*16+col, k = s*32+kk) at base_g + (s*NT_g + nt)*512 + col*32 + kk.
constexpr int K0 = 4352, K1 = 2560, K2 = 2304;   // S0=136, S1=80, S2=72
constexpr int WT1_OFF = 64*K0;              // 278528
constexpr int WT2_OFF = WT1_OFF + 32*K1;    // 360448

// ---------------------------------------------------------------------------
// Device helpers
// ---------------------------------------------------------------------------
using short8  = __attribute__((ext_vector_type(8))) short;
using float4v = __attribute__((ext_vector_type(4))) float;
using float2v = __attribute__((ext_vector_type(2))) float;

// RNE pack of two f32 -> packed 2x bf16 (one v_cvt_pk_bf16_f32).
__device__ __forceinline__ unsigned pkbf(float lo, float hi){
  unsigned r;
  asm("v_cvt_pk_bf16_f32 %0, %1, %2" : "=v"(r) : "v"(lo), "v"(hi));
  return r;
}

// Fragment from 4 float2 pairs (pair q = elements 2q, 2q+1).
__device__ __forceinline__ short8 mkfrag2(const float2v* s){
  union { short8 v; unsigned u[4]; } f;
  f.u[0] = pkbf(s[0][0], s[0][1]);
  f.u[1] = pkbf(s[1][0], s[1][1]);
  f.u[2] = pkbf(s[2][0], s[2][1]);
  f.u[3] = pkbf(s[3][0], s[3][1]);
  return f.v;
}

__device__ __forceinline__ short8 ldB(const unsigned short* p){
  return *reinterpret_cast<const short8*>(p);   // global_load_dwordx4
}

__device__ __forceinline__ float4v MFMA(short8 a, short8 b, float4v c){
  return __builtin_amdgcn_mfma_f32_16x16x32_bf16(a, b, c, 0, 0, 0);
}

__device__ __forceinline__ unsigned short f2bf_rne(float f){
  unsigned u = __builtin_bit_cast(unsigned, f);
  u += 0x7fffu + ((u >> 16) & 1u);
  return (unsigned short)(u >> 16);
}

// bf16 (LDS) -> f32: one shift.
__device__ __forceinline__ float bf2f(unsigned short h){
  return __builtin_bit_cast(float, (unsigned)h << 16);
}

// Packed f32 helpers (backend selects v_pk_mul_f32 / v_pk_fma_f32 on gfx950).
__device__ __forceinline__ float2v b2(float x){ return (float2v){x, x}; }
__device__ __forceinline__ float2v pfma(float2v a, float2v b, float2v c){
#if __has_builtin(__builtin_elementwise_fma)
  return __builtin_elementwise_fma(a, b, c);
#else
  return (float2v){ fmaf(a[0], b[0], c[0]), fmaf(a[1], b[1], c[1]) };
#endif
}

// Load N consecutive bf16 from LDS (16B-aligned, N multiple of 8) -> f32 regs.
template<int N>
__device__ __forceinline__ void ldw(const unsigned short* p, float* dst){
  #pragma unroll
  for (int q = 0; q < N/8; ++q){
    union { short8 v; unsigned short u[8]; } t;
    t.v = *reinterpret_cast<const short8*>(p + q*8);
    #pragma unroll
    for (int i = 0; i < 8; ++i) dst[q*8 + i] = bf2f(t.u[i]);
  }
}

// Same, but into float2 pairs (dst[q] = {elem 2q, elem 2q+1}).
template<int N>
__device__ __forceinline__ void ldw2(const unsigned short* p, float2v* dst){
  #pragma unroll
  for (int q = 0; q < N/8; ++q){
    union { short8 v; unsigned short u[8]; } t;
    t.v = *reinterpret_cast<const short8*>(p + q*8);
    #pragma unroll
    for (int i = 0; i < 4; ++i)
      dst[q*4 + i] = (float2v){ bf2f(t.u[2*i]), bf2f(t.u[2*i+1]) };
  }
}

#define NZ(c) ((c) > 1e-12 || (c) < -1e-12)

constexpr int XSH = 248;  // x-tile LDS row stride (ushorts): 496B, 2-way banks

// ---------------------------------------------------------------------------
// Weight preprocessing v3: folded + fragment-tiled (identical to round 7).
// grid (136, 3), block 256.
// ---------------------------------------------------------------------------
__global__ __launch_bounds__(256)
void tsq_prep(const float* __restrict__ w0, const float* __restrict__ w1,
              const float* __restrict__ w2, const float* __restrict__ w3,
              const float* __restrict__ w4, const float* __restrict__ w5,
              const float* __restrict__ w6, const float* __restrict__ w7,
              const float* __restrict__ w8, const float* __restrict__ w9,
              const float* __restrict__ w10, unsigned short* __restrict__ wt){
  const int s   = blockIdx.x;
  const int g   = blockIdx.y;
  const int tid = threadIdx.x;

  const int lw  = 6 - g;                 // log2(Wn): 6,5,4
  const int Wn  = 1 << lw;               // 64,32,16
  const int NT  = Wn >> 4;               // 4,2,1
  int Smax;
  unsigned short* obase;
  if (g == 0){ Smax = 136; obase = wt; }
  else if (g == 1){ Smax = 80; obase = wt + WT1_OFF; }
  else { Smax = 72; obase = wt + WT2_OFF; }
  if (s >= Smax) return;

  __shared__ unsigned short tl[32*66];   // max 32 x (64+2)
  const int st = Wn + 2;

  // ---- phase 1: gather/scale/convert (with mirror folds), coalesced in n ----
  const int nel = 32 << lw;              // == NT*512
  for (int idx = tid; idx < nel; idx += 256){
    const int kk = idx >> lw, n = idx & (Wn - 1);
    float v;
    if (g == 0){
      if (s < 64){                                   // (0,0,0) u<32, all v
        const int u = s >> 1, vv = (s & 1)*32 + kk;
        v = w0[(u*64 + vv)*64 + n];
        if (s & 1) v += w0[(vv*64 + u)*64 + n];      // fold dropped (u>=32,v<32)
        v *= (float)S000;
      } else if (s < 96){                            // (0,0,0) u>=32, v>=32
        const int u = s - 32, vv = 32 + kk;
        v = w0[(u*64 + vv)*64 + n] * (float)S000;
      } else if (s < 128){                           // (1,1,0) K=u*32+v
        v = w4[((s-96)*32 + kk)*64 + n] * (float)S110;
      } else {                                       // (2,2,0) K=u*16+v
        v = w9[((s-128)*32 + kk)*64 + n] * (float)S220;
      }
    } else if (g == 1){
      const int k = s*32 + kk;
      if (s < 64){                                   // (0,1,1)+(1,0,1), K=A1*64+A0
        v = w1[((k&63)*32 + (k>>6))*32 + n] * (float)S011
          + w3[k*32 + n] * (float)S101;
      } else {                                       // (1,2,1)+(2,1,1), K=v2*32+u1
        const int kr = k - 2048;
        const int u1 = kr & 31, v2 = kr >> 5;
        v = w6[(u1*16 + v2)*32 + n] * (float)S121
          + w8[(v2*32 + u1)*32 + n] * (float)S211;
      }
    } else {
      const int k = s*32 + kk;
      if (s < 32){                                   // (0,2,2)+(2,0,2), K=v2*64+u0
        v = w2[((k&63)*16 + (k>>6))*16 + n] * (float)S022
          + w7[k*16 + n] * (float)S202;
      } else if (s < 64){                            // (1,1,2) K=u*32+v
        v = w5[(k-1024)*16 + n] * (float)S112;
      } else {                                       // (2,2,2) K=u*16+v
        v = w10[(k-2048)*16 + n] * (float)S222;
      }
    }
    tl[kk*st + n] = f2bf_rne(v);
  }
  __syncthreads();

  // ---- phase 2: contiguous fragment-order write ----
  unsigned short* o = obase + (size_t)s*NT*512;
  const int nout = NT*512;
  for (int idx = tid; idx < nout; idx += 256){
    const int nt  = idx >> 9;
    const int r   = idx & 511;
    const int col = r >> 5;
    const int kk  = r & 31;
    o[idx] = tl[kk*st + nt*16 + col];
  }
}

// ---------------------------------------------------------------------------
// Main kernel.  grid (313, 3), block 512 (8 waves).  blockIdx.y = GEMM id
// (g0 dispatched first = LPT), blockIdx.x = batch tile of 64 rows.
// x tile staged in LDS as bf16 (RNE).  Hot loops chunked 2x: both
// sub-iterations' B fragments load into distinct arrays up front.
// ---------------------------------------------------------------------------
__global__ __launch_bounds__(512, 4)
void tsq_main(const float* __restrict__ x, const unsigned short* __restrict__ wt,
              float* __restrict__ out){
  __shared__ unsigned short lxh[64*XSH];
  const int g    = blockIdx.y;
  const int b0   = blockIdx.x * 64;
  const int tid  = threadIdx.x;
  const int wv   = tid >> 6;      // 0..7
  const int lane = tid & 63;
  const int col  = lane & 15;
  const int tg   = lane >> 4;
  const int fo   = col*32 + tg*8; // per-lane fragment offset within a 512-el tile

  // ---- stage x tile: f32 global -> RNE bf16 LDS (uint2 = 4 elems / store) ----
  for (int i = tid; i < 64*60; i += 512){
    const int r = i / 60, c = i - r*60;
    int gb = b0 + r; if (gb > 19999) gb = 19999;
    const float4 v = *(reinterpret_cast<const float4*>(x + (size_t)gb*240) + c);
    uint2 p; p.x = pkbf(v.x, v.y); p.y = pkbf(v.z, v.w);
    *reinterpret_cast<uint2*>(&lxh[r*XSH + c*4]) = p;
  }
  __syncthreads();

  const float4v z4 = {0.f, 0.f, 0.f, 0.f};

  if (g == 0){
    // ====== GEMM 0: out[:,0:64], K=4352, 2-way M (mh) x 4-way K (kh) ======
    const unsigned short* bpl = wt + fo;
    const int mh  = wv >> 2;
    const int kh  = wv & 3;
    const int par = kh & 1;       // s-parity for s<64 (constant per wave)

    float4v acc[2][4];
    #pragma unroll
    for (int mt = 0; mt < 2; ++mt)
      #pragma unroll
      for (int nt = 0; nt < 4; ++nt) acc[mt][nt] = z4;

    const unsigned short* rbase[2];
    #pragma unroll
    for (int mt = 0; mt < 2; ++mt) rbase[mt] = &lxh[(mh*32 + mt*16 + col)*XSH];

    // wA = x0 window for parity `par` (s<64); wB = x0 upper half (s>=64).
    float2v wA[2][4], wB[2][4];
    #pragma unroll
    for (int mt = 0; mt < 2; ++mt){
      ldw2<8>(rbase[mt] + par*32 + tg*8, wA[mt]);
      ldw2<8>(rbase[mt] + 32 + tg*8,     wB[mt]);
    }

    // --- (0,0,0) part A: s in [0,64) step 4, chunk=2 (16 iters -> 8 chunks) ---
    for (int s = kh; s < 64; s += 8){
      short8 bfA[4], bfB[4];
      #pragma unroll
      for (int nt = 0; nt < 4; ++nt) bfA[nt] = ldB(bpl + ((s    )*4 + nt)*512);
      #pragma unroll
      for (int nt = 0; nt < 4; ++nt) bfB[nt] = ldB(bpl + ((s + 4)*4 + nt)*512);
      float xuA[2], xuB[2];
      xuA[0] = bf2f(rbase[0][s >> 1]);       xuA[1] = bf2f(rbase[1][s >> 1]);
      xuB[0] = bf2f(rbase[0][(s + 4) >> 1]); xuB[1] = bf2f(rbase[1][(s + 4) >> 1]);
      #pragma unroll
      for (int mt = 0; mt < 2; ++mt){
        const float2v xu2 = b2(xuA[mt]);
        float2v sv[4];
        #pragma unroll
        for (int q = 0; q < 4; ++q) sv[q] = xu2 * wA[mt][q];
        const short8 af = mkfrag2(sv);
        #pragma unroll
        for (int nt = 0; nt < 4; ++nt) acc[mt][nt] = MFMA(af, bfA[nt], acc[mt][nt]);
      }
      #pragma unroll
      for (int mt = 0; mt < 2; ++mt){
        const float2v xu2 = b2(xuB[mt]);
        float2v sv[4];
        #pragma unroll
        for (int q = 0; q < 4; ++q) sv[q] = xu2 * wA[mt][q];
        const short8 af = mkfrag2(sv);
        #pragma unroll
        for (int nt = 0; nt < 4; ++nt) acc[mt][nt] = MFMA(af, bfB[nt], acc[mt][nt]);
      }
    }
    // --- (0,0,0) part B: s in [64,96) step 4, chunk=2 (8 iters -> 4 chunks) ---
    for (int s = 64 + kh; s < 96; s += 8){
      short8 bfA[4], bfB[4];
      #pragma unroll
      for (int nt = 0; nt < 4; ++nt) bfA[nt] = ldB(bpl + ((s    )*4 + nt)*512);
      #pragma unroll
      for (int nt = 0; nt < 4; ++nt) bfB[nt] = ldB(bpl + ((s + 4)*4 + nt)*512);
      float xuA[2], xuB[2];
      xuA[0] = bf2f(rbase[0][s - 32]);     xuA[1] = bf2f(rbase[1][s - 32]);
      xuB[0] = bf2f(rbase[0][s - 32 + 4]); xuB[1] = bf2f(rbase[1][s - 32 + 4]);
      #pragma unroll
      for (int mt = 0; mt < 2; ++mt){
        const float2v xu2 = b2(xuA[mt]);
        float2v sv[4];
        #pragma unroll
        for (int q = 0; q < 4; ++q) sv[q] = xu2 * wB[mt][q];
        const short8 af = mkfrag2(sv);
        #pragma unroll
        for (int nt = 0; nt < 4; ++nt) acc[mt][nt] = MFMA(af, bfA[nt], acc[mt][nt]);
      }
      #pragma unroll
      for (int mt = 0; mt < 2; ++mt){
        const float2v xu2 = b2(xuB[mt]);
        float2v sv[4];
        #pragma unroll
        for (int q = 0; q < 4; ++q) sv[q] = xu2 * wB[mt][q];
        const short8 af = mkfrag2(sv);
        #pragma unroll
        for (int nt = 0; nt < 4; ++nt) acc[mt][nt] = MFMA(af, bfB[nt], acc[mt][nt]);
      }
    }
    // --- (1,1,0): s in [96,128) step 4, chunk=2 (8 iters -> 4 chunks) ---
    float2v x1A[2][4], x1B[2][4], x1C[2][4];
    #pragma unroll
    for (int mt = 0; mt < 2; ++mt){
      float tmp[24];
      ldw<24>(rbase[mt] + 64 + tg*24, tmp);
      #pragma unroll
      for (int q = 0; q < 4; ++q){
        x1A[mt][q] = (float2v){ tmp[(2*q)*3+0], tmp[(2*q+1)*3+0] };
        x1B[mt][q] = (float2v){ tmp[(2*q)*3+1], tmp[(2*q+1)*3+1] };
        x1C[mt][q] = (float2v){ tmp[(2*q)*3+2], tmp[(2*q+1)*3+2] };
      }
    }
    for (int s = 96 + kh; s < 128; s += 8){
      short8 bfA[4], bfB[4];
      #pragma unroll
      for (int nt = 0; nt < 4; ++nt) bfA[nt] = ldB(bpl + ((s    )*4 + nt)*512);
      #pragma unroll
      for (int nt = 0; nt < 4; ++nt) bfB[nt] = ldB(bpl + ((s + 4)*4 + nt)*512);
      const int uA = s - 96, uB = uA + 4;
      float ucA[2][3], ucB[2][3];
      #pragma unroll
      for (int mt = 0; mt < 2; ++mt){
        ucA[mt][0] = bf2f(rbase[mt][64+uA*3]);
        ucA[mt][1] = bf2f(rbase[mt][64+uA*3+1]);
        ucA[mt][2] = bf2f(rbase[mt][64+uA*3+2]);
        ucB[mt][0] = bf2f(rbase[mt][64+uB*3]);
        ucB[mt][1] = bf2f(rbase[mt][64+uB*3+1]);
        ucB[mt][2] = bf2f(rbase[mt][64+uB*3+2]);
      }
      #pragma unroll
      for (int mt = 0; mt < 2; ++mt){
        const float2v u0 = b2(ucA[mt][0]), u1 = b2(ucA[mt][1]), u2 = b2(ucA[mt][2]);
        float2v sv[4];
        #pragma unroll
        for (int q = 0; q < 4; ++q)
          sv[q] = pfma(u0, x1A[mt][q], pfma(u1, x1B[mt][q], u2 * x1C[mt][q]));
        const short8 af = mkfrag2(sv);
        #pragma unroll
        for (int nt = 0; nt < 4; ++nt) acc[mt][nt] = MFMA(af, bfA[nt], acc[mt][nt]);
      }
      #pragma unroll
      for (int mt = 0; mt < 2; ++mt){
        const float2v u0 = b2(ucB[mt][0]), u1 = b2(ucB[mt][1]), u2 = b2(ucB[mt][2]);
        float2v sv[4];
        #pragma unroll
        for (int q = 0; q < 4; ++q)
          sv[q] = pfma(u0, x1A[mt][q], pfma(u1, x1B[mt][q], u2 * x1C[mt][q]));
        const short8 af = mkfrag2(sv);
        #pragma unroll
        for (int nt = 0; nt < 4; ++nt) acc[mt][nt] = MFMA(af, bfB[nt], acc[mt][nt]);
      }
    }
    // --- (2,2,0): s in [128,136), K=u*16+v (2 iters: scalar, unchunked) ---
    for (int s = 128 + kh; s < 136; s += 4){
      short8 bf[4];
      #pragma unroll
      for (int nt = 0; nt < 4; ++nt) bf[nt] = ldB(bpl + (s*4 + nt)*512);
      const int ub = (s - 128)*2 + (tg >> 1);
      #pragma unroll
      for (int mt = 0; mt < 2; ++mt){
        const unsigned short* rb = rbase[mt];
        float xu[5];
        #pragma unroll
        for (int i = 0; i < 5; ++i) xu[i] = bf2f(rb[160 + ub*5 + i]);
        float xv[40];
        ldw<40>(rb + 160 + (tg&1)*40, xv);
        float sv[8];
        #pragma unroll
        for (int t = 0; t < 8; ++t){
          float a = 0.f;
          #pragma unroll
          for (int i = 0; i < 5; ++i) a = fmaf(xu[i], xv[t*5+i], a);
          sv[t] = a;
        }
        union { short8 v; unsigned u[4]; } f;
        f.u[0] = pkbf(sv[0], sv[1]); f.u[1] = pkbf(sv[2], sv[3]);
        f.u[2] = pkbf(sv[4], sv[5]); f.u[3] = pkbf(sv[6], sv[7]);
        #pragma unroll
        for (int nt = 0; nt < 4; ++nt) acc[mt][nt] = MFMA(f.v, bf[nt], acc[mt][nt]);
      }
    }
    // --- 4-way K reduction, 3 passes of 16 KB (scratch = lxh as f32) ---
    __syncthreads();
    float* red = reinterpret_cast<float*>(lxh);
    #pragma unroll
    for (int p = 1; p <= 3; ++p){
      if (kh == p){
        #pragma unroll
        for (int mt = 0; mt < 2; ++mt)
          #pragma unroll
          for (int nt = 0; nt < 4; ++nt)
            #pragma unroll
            for (int r = 0; r < 4; ++r)
              red[mh*2048 + (mt*4 + nt)*256 + (tg*4 + r)*16 + col] = acc[mt][nt][r];
      }
      __syncthreads();
      if (kh == 0){
        #pragma unroll
        for (int mt = 0; mt < 2; ++mt)
          #pragma unroll
          for (int nt = 0; nt < 4; ++nt)
            #pragma unroll
            for (int r = 0; r < 4; ++r)
              acc[mt][nt][r] += red[mh*2048 + (mt*4 + nt)*256 + (tg*4 + r)*16 + col];
      }
      __syncthreads();
    }
    if (kh == 0){
      #pragma unroll
      for (int mt = 0; mt < 2; ++mt)
        #pragma unroll
        for (int r = 0; r < 4; ++r){
          const int b = b0 + mh*32 + mt*16 + tg*4 + r;
          if (b < 20000){
            #pragma unroll
            for (int nt = 0; nt < 4; ++nt)
              out[(size_t)b*240 + nt*16 + col] = acc[mt][nt][r];
          }
        }
    }

  } else if (g == 1){
    // ===== GEMM 1: out[:,64:160] (w*3+k), K=2560, 4-way M (mq) x 2-way K =====
    const unsigned short* bpl = wt + WT1_OFF + fo;
    const int mq = wv >> 1;
    const int kh = wv & 1;
    const unsigned short* rb = &lxh[(mq*16 + col)*XSH];

    float4v acc[3][2];
    #pragma unroll
    for (int k3 = 0; k3 < 3; ++k3)
      #pragma unroll
      for (int nt = 0; nt < 2; ++nt) acc[k3][nt] = z4;

    float2v w2[4];
    ldw2<8>(rb + kh*32 + tg*8, w2);
    float2v x1A[4], x1B[4], x1C[4];
    {
      float tmp[24];
      ldw<24>(rb + 64 + tg*24, tmp);
      #pragma unroll
      for (int q = 0; q < 4; ++q){
        x1A[q] = (float2v){ tmp[(2*q)*3+0], tmp[(2*q+1)*3+0] };
        x1B[q] = (float2v){ tmp[(2*q)*3+1], tmp[(2*q+1)*3+1] };
        x1C[q] = (float2v){ tmp[(2*q)*3+2], tmp[(2*q+1)*3+2] };
      }
    }

    // --- (0,1,1)+(1,0,1) folded: s in [0,64) step 2, chunk=2 (32->16) ---
    for (int s = kh; s < 64; s += 4){
      const int sB = s + 2;
      const short8 a0A = ldB(bpl + (s*2    )*512);
      const short8 a1A = ldB(bpl + (s*2 + 1)*512);
      const short8 a0B = ldB(bpl + (sB*2    )*512);
      const short8 a1B = ldB(bpl + (sB*2 + 1)*512);
      const int mA = s >> 1, mB = sB >> 1;
      const float cA0 = bf2f(rb[64+mA*3]), cA1 = bf2f(rb[64+mA*3+1]), cA2 = bf2f(rb[64+mA*3+2]);
      const float cB0 = bf2f(rb[64+mB*3]), cB1 = bf2f(rb[64+mB*3+1]), cB2 = bf2f(rb[64+mB*3+2]);
      {
        const float2v c0 = b2(cA0), c1 = b2(cA1), c2 = b2(cA2);
        float2v sv0[4], sv1[4], sv2[4];
        #pragma unroll
        for (int q = 0; q < 4; ++q){
          sv0[q] = w2[q]*c0; sv1[q] = w2[q]*c1; sv2[q] = w2[q]*c2;
        }
        const short8 f0 = mkfrag2(sv0), f1 = mkfrag2(sv1), f2 = mkfrag2(sv2);
        acc[0][0] = MFMA(f0, a0A, acc[0][0]);
        acc[0][1] = MFMA(f0, a1A, acc[0][1]);
        acc[1][0] = MFMA(f1, a0A, acc[1][0]);
        acc[1][1] = MFMA(f1, a1A, acc[1][1]);
        acc[2][0] = MFMA(f2, a0A, acc[2][0]);
        acc[2][1] = MFMA(f2, a1A, acc[2][1]);
      }
      {
        const float2v c0 = b2(cB0), c1 = b2(cB1), c2 = b2(cB2);
        float2v sv0[4], sv1[4], sv2[4];
        #pragma unroll
        for (int q = 0; q < 4; ++q){
          sv0[q] = w2[q]*c0; sv1[q] = w2[q]*c1; sv2[q] = w2[q]*c2;
        }
        const short8 f0 = mkfrag2(sv0), f1 = mkfrag2(sv1), f2 = mkfrag2(sv2);
        acc[0][0] = MFMA(f0, a0B, acc[0][0]);
        acc[0][1] = MFMA(f0, a1B, acc[0][1]);
        acc[1][0] = MFMA(f1, a0B, acc[1][0]);
        acc[1][1] = MFMA(f1, a1B, acc[1][1]);
        acc[2][0] = MFMA(f2, a0B, acc[2][0]);
        acc[2][1] = MFMA(f2, a1B, acc[2][1]);
      }
    }
    // --- (1,2,1)+(2,1,1) folded: s in [64,80) step 2, chunk=2 (8->4) ---
    for (int s = 64 + kh; s < 80; s += 4){
      const int sB = s + 2;
      const short8 a0A = ldB(bpl + (s*2    )*512);
      const short8 a1A = ldB(bpl + (s*2 + 1)*512);
      const short8 a0B = ldB(bpl + (sB*2    )*512);
      const short8 a1B = ldB(bpl + (sB*2 + 1)*512);
      float xqA[5], xqB[5];
      #pragma unroll
      for (int j = 0; j < 5; ++j){
        xqA[j] = bf2f(rb[160 + (s - 64)*5 + j]);
        xqB[j] = bf2f(rb[160 + (sB - 64)*5 + j]);
      }
      #pragma unroll
      for (int half = 0; half < 2; ++half){
        const float* xq = half ? xqB : xqA;
        const short8 b0h = half ? a0B : a0A;
        const short8 b1h = half ? a1B : a1A;
        float t3[3][3];
        #pragma unroll
        for (int kk = 0; kk < 3; ++kk)
          #pragma unroll
          for (int i = 0; i < 3; ++i){
            float a = 0.f;
            #pragma unroll
            for (int j = 0; j < 5; ++j){
              const double cd = T121.v[i][j][kk];
              if (NZ(cd)) a = fmaf((float)cd, xq[j], a);
            }
            t3[kk][i] = a;
          }
        float2v sv0[4], sv1[4], sv2[4];
        {
          const float2v t00 = b2(t3[0][0]), t01 = b2(t3[0][1]), t02 = b2(t3[0][2]);
          const float2v t10 = b2(t3[1][0]), t11 = b2(t3[1][1]), t12 = b2(t3[1][2]);
          const float2v t20 = b2(t3[2][0]), t21 = b2(t3[2][1]), t22 = b2(t3[2][2]);
          #pragma unroll
          for (int q = 0; q < 4; ++q){
            sv0[q] = pfma(x1A[q], t00, pfma(x1B[q], t01, x1C[q]*t02));
            sv1[q] = pfma(x1A[q], t10, pfma(x1B[q], t11, x1C[q]*t12));
            sv2[q] = pfma(x1A[q], t20, pfma(x1B[q], t21, x1C[q]*t22));
          }
        }
        const short8 f0 = mkfrag2(sv0), f1 = mkfrag2(sv1), f2 = mkfrag2(sv2);
        acc[0][0] = MFMA(f0, b0h, acc[0][0]);
        acc[0][1] = MFMA(f0, b1h, acc[0][1]);
        acc[1][0] = MFMA(f1, b0h, acc[1][0]);
        acc[1][1] = MFMA(f1, b1h, acc[1][1]);
        acc[2][0] = MFMA(f2, b0h, acc[2][0]);
        acc[2][1] = MFMA(f2, b1h, acc[2][1]);
      }
    }
    // --- 2-way K reduction + store (3 consecutive floats per (b,w)) ---
    __syncthreads();
    float* red = reinterpret_cast<float*>(lxh);
    if (kh == 1){
      #pragma unroll
      for (int k3 = 0; k3 < 3; ++k3)
        #pragma unroll
        for (int nt = 0; nt < 2; ++nt)
          #pragma unroll
          for (int r = 0; r < 4; ++r)
            red[mq*1536 + (k3*2 + nt)*256 + (tg*4 + r)*16 + col] = acc[k3][nt][r];
    }
    __syncthreads();
    if (kh == 0){
      #pragma unroll
      for (int r = 0; r < 4; ++r){
        const int b = b0 + mq*16 + tg*4 + r;
        if (b < 20000){
          #pragma unroll
          for (int nt = 0; nt < 2; ++nt){
            const int w2i = nt*16 + col;
            float* o = out + (size_t)b*240 + 64 + 3*w2i;
            #pragma unroll
            for (int k3 = 0; k3 < 3; ++k3)
              o[k3] = acc[k3][nt][r]
                    + red[mq*1536 + (k3*2 + nt)*256 + (tg*4 + r)*16 + col];
          }
        }
      }
    }

  } else {
    // ===== GEMM 2: out[:,160:240] (w*5+k), K=2304, 4-way M (mq) x 2-way K =====
    const unsigned short* bpl = wt + WT2_OFF + fo;
    const int mq = wv >> 1;
    const int kh = wv & 1;
    const unsigned short* rb = &lxh[(mq*16 + col)*XSH];

    float4v acc[5] = { z4, z4, z4, z4, z4 };

    float2v w2[4];
    ldw2<8>(rb + kh*32 + tg*8, w2);
    float2v x1A[4], x1B[4], x1C[4];
    {
      float tmp[24];
      ldw<24>(rb + 64 + tg*24, tmp);
      #pragma unroll
      for (int q = 0; q < 4; ++q){
        x1A[q] = (float2v){ tmp[(2*q)*3+0], tmp[(2*q+1)*3+0] };
        x1B[q] = (float2v){ tmp[(2*q)*3+1], tmp[(2*q+1)*3+1] };
        x1C[q] = (float2v){ tmp[(2*q)*3+2], tmp[(2*q+1)*3+2] };
      }
    }

    // --- (0,2,2)+(2,0,2) folded: s in [0,32) step 2, chunk=2 (16->8) ---
    for (int s = kh; s < 32; s += 4){
      const int sB = s + 2;
      const short8 bfA = ldB(bpl + s*512);
      const short8 bfB = ldB(bpl + sB*512);
      float xqA[5], xqB[5];
      #pragma unroll
      for (int j = 0; j < 5; ++j){
        xqA[j] = bf2f(rb[160 + (s >> 1)*5 + j]);
        xqB[j] = bf2f(rb[160 + (sB >> 1)*5 + j]);
      }
      {
        float2v sv[5][4];
        #pragma unroll
        for (int k5 = 0; k5 < 5; ++k5){
          const float2v xq2 = b2(xqA[k5]);
          #pragma unroll
          for (int q = 0; q < 4; ++q) sv[k5][q] = w2[q] * xq2;
        }
        #pragma unroll
        for (int k5 = 0; k5 < 5; ++k5) acc[k5] = MFMA(mkfrag2(sv[k5]), bfA, acc[k5]);
      }
      {
        float2v sv[5][4];
        #pragma unroll
        for (int k5 = 0; k5 < 5; ++k5){
          const float2v xq2 = b2(xqB[k5]);
          #pragma unroll
          for (int q = 0; q < 4; ++q) sv[k5][q] = w2[q] * xq2;
        }
        #pragma unroll
        for (int k5 = 0; k5 < 5; ++k5) acc[k5] = MFMA(mkfrag2(sv[k5]), bfB, acc[k5]);
      }
    }
    // --- (1,1,2): s in [32,64) step 2, chunk=2 (16->8), precontracted ---
    for (int s = 32 + kh; s < 64; s += 4){
      const int sB = s + 2;
      const short8 bfA = ldB(bpl + s*512);
      const short8 bfB = ldB(bpl + sB*512);
      float xuA[3], xuB[3];
      #pragma unroll
      for (int i = 0; i < 3; ++i){
        xuA[i] = bf2f(rb[64 + (s - 32)*3 + i]);
        xuB[i] = bf2f(rb[64 + (sB - 32)*3 + i]);
      }
      #pragma unroll
      for (int half = 0; half < 2; ++half){
        const float* xu = half ? xuB : xuA;
        const short8 bfh = half ? bfB : bfA;
        float t5[5][3];
        #pragma unroll
        for (int kk = 0; kk < 5; ++kk)
          #pragma unroll
          for (int j = 0; j < 3; ++j){
            float a = 0.f;
            #pragma unroll
            for (int i = 0; i < 3; ++i){
              const double cd = T112.v[i][j][kk];
              if (NZ(cd)) a = fmaf((float)cd, xu[i], a);
            }
            t5[kk][j] = a;
          }
        float2v sv[5][4];
        #pragma unroll
        for (int kk = 0; kk < 5; ++kk){
          const float2v c0 = b2(t5[kk][0]), c1 = b2(t5[kk][1]), c2 = b2(t5[kk][2]);
          #pragma unroll
          for (int q = 0; q < 4; ++q)
            sv[kk][q] = pfma(x1A[q], c0, pfma(x1B[q], c1, x1C[q]*c2));
        }
        #pragma unroll
        for (int k5 = 0; k5 < 5; ++k5) acc[k5] = MFMA(mkfrag2(sv[k5]), bfh, acc[k5]);
      }
    }
    // --- (2,2,2): s in [64,72), K=u*16+v, precontracted per-lane ---
    {
      // x2 window transposed: tV[j][q] = component j of rows (2q, 2q+1).
      float2v tV[5][4];
      {
        float x2w[40];
        ldw<40>(rb + 160 + (tg&1)*40, x2w);
        #pragma unroll
        for (int j = 0; j < 5; ++j)
          #pragma unroll
          for (int q = 0; q < 4; ++q)
            tV[j][q] = (float2v){ x2w[(2*q)*5+j], x2w[(2*q+1)*5+j] };
      }
      for (int s = 64 + kh; s < 72; s += 2){
        const short8 bf = ldB(bpl + s*512);
        const int ub = (s - 64)*2 + (tg >> 1);
        float xu[5];
        #pragma unroll
        for (int i = 0; i < 5; ++i) xu[i] = bf2f(rb[160 + ub*5 + i]);
        // t5[kk][j] = sum_i C222[i][j][kk] * xu[i]
        float t5[5][5];
        #pragma unroll
        for (int kk = 0; kk < 5; ++kk)
          #pragma unroll
          for (int j = 0; j < 5; ++j){
            float a = 0.f;
            #pragma unroll
            for (int i = 0; i < 5; ++i){
              const double cd = T222.v[i][j][kk];
              if (NZ(cd)) a = fmaf((float)cd, xu[i], a);
            }
            t5[kk][j] = a;
          }
        float2v sv[5][4];
        #pragma unroll
        for (int kk = 0; kk < 5; ++kk){
          float2v a[4];
          const float2v c0 = b2(t5[kk][0]);
          #pragma unroll
          for (int q = 0; q < 4; ++q) a[q] = tV[0][q] * c0;
          #pragma unroll
          for (int j = 1; j < 5; ++j){
            const float2v cj = b2(t5[kk][j]);
            #pragma unroll
            for (int q = 0; q < 4; ++q) a[q] = pfma(tV[j][q], cj, a[q]);
          }
          #pragma unroll
          for (int q = 0; q < 4; ++q) sv[kk][q] = a[q];
        }
        #pragma unroll
        for (int k5 = 0; k5 < 5; ++k5) acc[k5] = MFMA(mkfrag2(sv[k5]), bf, acc[k5]);
      }
    }
    // --- 2-way K reduction + store (5 consecutive floats per (b,w)) ---
    __syncthreads();
    float* red = reinterpret_cast<float*>(lxh);
    if (kh == 1){
      #pragma unroll
      for (int k5 = 0; k5 < 5; ++k5)
        #pragma unroll
        for (int r = 0; r < 4; ++r)
          red[mq*1280 + k5*256 + (tg*4 + r)*16 + col] = acc[k5][r];
    }
    __syncthreads();
    if (kh == 0){
      #pragma unroll
      for (int r = 0; r < 4; ++r){
        const int b = b0 + mq*16 + tg*4 + r;
        if (b < 20000){
          float* o = out + (size_t)b*240 + 160 + 5*col;
          #pragma unroll
          for (int k5 = 0; k5 < 5; ++k5)
            o[k5] = acc[k5][r] + red[mq*1280 + k5*256 + (tg*4 + r)*16 + col];
        }
      }
    }
  }
}

// ---------------------------------------------------------------------------
extern "C" void kernel_launch(void* const* d_in, const int* in_sizes, int n_in,
                              void* d_out, int out_size, void* d_ws, size_t ws_size,
                              hipStream_t stream){
  (void)in_sizes; (void)n_in; (void)out_size; (void)ws_size;
  const float* x = (const float*)d_in[0];
  const float* w[11];
  for (int i = 0; i < 11; ++i) w[i] = (const float*)d_in[1 + i];
  unsigned short* wt = (unsigned short*)d_ws;
  float* out = (float*)d_out;

  dim3 gp(136, 3);
  tsq_prep<<<gp, 256, 0, stream>>>(w[0], w[1], w[2], w[3], w[4], w[5],
                                   w[6], w[7], w[8], w[9], w[10], wt);
  dim3 gm(313, 3);   // x = tile (fastest), y = g: all g0 (longest) first = LPT
  tsq_main<<<gm, 512, 0, stream>>>(x, wt, out);
}